// Round 16
// baseline (604.726 us; speedup 1.0000x reference)
//
#include <hip/hip_runtime.h>
#include <math.h>

typedef float float4v __attribute__((ext_vector_type(4)));
typedef __attribute__((ext_vector_type(4))) float f32x4;
typedef __attribute__((ext_vector_type(8))) short short8v;
typedef __attribute__((ext_vector_type(8))) unsigned short ushort8v;

#define NROW 8192
#define FEAT 200
#define OUTC 300
#define ZLD  256
#define HLK  448
#define HLN  384

__device__ __forceinline__ unsigned short f2bf(float x) {
  unsigned u = __float_as_uint(x);
  return (unsigned short)((u + 0x7fffu + ((u >> 16) & 1u)) >> 16);  // RNE
}

// ===========================================================================
// zmul_t (stage 0): Zt0[j][row] = bf16(x @ W blockdiag).
// ===========================================================================
__global__ __launch_bounds__(256) void zmul_t_kernel(
    const float* __restrict__ x, const float* __restrict__ W,
    unsigned short* __restrict__ Zt) {
  __shared__ float Ws[2500];
  __shared__ float hs[16][200];
  __shared__ float zbuf[16][256];
  int t = threadIdx.x;
  int r0 = blockIdx.x * 16;
  for (int i = t; i < 2500; i += 256) Ws[i] = W[i];
  for (int i = t; i < 16 * FEAT; i += 256)
    hs[0][i] = x[(size_t)r0 * FEAT + i];
  __syncthreads();
  for (int i = t; i < 16 * 256; i += 256) {
    int row = i >> 8, j = i & 255;
    float acc = 0.f;
    if (j < FEAT) {
      int s = j / 50, jj = j % 50;
      const float* hrow = &hs[row][s * 50];
      #pragma unroll 5
      for (int k = 0; k < 50; ++k) acc += hrow[k] * Ws[k * 50 + jj];
    }
    zbuf[row][j] = acc;
  }
  __syncthreads();
  unsigned int* Ztu = (unsigned int*)Zt;
  for (int i = t; i < 256 * 8; i += 256) {
    int j = i >> 3, w2 = i & 7;
    unsigned int lo = f2bf(zbuf[2 * w2][j]);
    unsigned int hi = f2bf(zbuf[2 * w2 + 1][j]);
    Ztu[((j * NROW + r0) >> 1) + w2] = lo | (hi << 16);
  }
}

// ===========================================================================
// gemm_cvt_spill (round-13 best config + NT f32 loads): stage-0 GEMMs,
// RAW F32 A read with NON-TEMPORAL hint (stream-once; keep L2/L3 for the
// bf16 spill that gemm_pair re-reads). 128x128/BK=64/dbuf-64KB, 512 thr
// (8 waves -> 4 waves/SIMD at 2 blk/CU), in-kernel cvt_pk RNE, balanced
// spill (cb==0: tiles [0,32), cb==1: [32,64)).
// ===========================================================================
__global__ __launch_bounds__(512, 4) void gemm_cvt_spill_kernel(
    const float* __restrict__ AF, const float* __restrict__ AS,
    const unsigned short* __restrict__ ZtF,
    const unsigned short* __restrict__ ZtS,
    float* __restrict__ Cpart,
    unsigned short* __restrict__ AbF_o, unsigned short* __restrict__ AbS_o) {
  int d = blockIdx.x;                 // 0..511
  int L = (d & 7) * 64 + (d >> 3);    // XCD-chunked bijective
  int mat = L & 1;
  int ks  = (L >> 1) & 1;
  int cb  = (L >> 2) & 1;
  int rb  = L >> 3;                   // 0..63

  const float* __restrict__ A = mat ? AS : AF;
  const unsigned short* __restrict__ Zt = mat ? ZtS : ZtF;
  unsigned short* __restrict__ Abo = mat ? AbS_o : AbF_o;

  int t = threadIdx.x;                // 0..511
  int lane = t & 63, wv = t >> 6;     // wv 0..7
  int row0 = rb * 128, n0 = cb * 128, k0 = ks * 4096;

  __shared__ short As[2][128 * 64];
  __shared__ short Bs[2][128 * 64];

  // A reg-staging: 1024 bf16 16B chunks, 2 per thread.
  int srcAf[2], dstA[2];
  #pragma unroll
  for (int i = 0; i < 2; ++i) {
    int cc = i * 512 + t;
    int m = cc >> 3, s = cc & 7;
    srcAf[i] = (row0 + m) * NROW + s * 8;
    dstA[i] = m * 64 + ((s ^ (m & 7)) * 8);
  }
  // B staging via global_load_lds: 1024 chunks, 2 per thread.
  int srcB[2], ldsDstB[2];
  #pragma unroll
  for (int i = 0; i < 2; ++i) {
    int c = i * 512 + t;
    int m = c >> 3, sl = c & 7;
    srcB[i] = (n0 + m) * NROW + ((sl ^ (m & 7)) * 8);
    ldsDstB[i] = (i * 512 + wv * 64) * 8;
  }

  f32x4 ar0[2], ar1[2];   // 2 chunks in flight (16 VGPR)

#define STAGE_B(buf, kt)                                                              \
  {                                                                                   \
    _Pragma("unroll")                                                                 \
    for (int i = 0; i < 2; ++i)                                                       \
      __builtin_amdgcn_global_load_lds(                                               \
          (const __attribute__((address_space(1))) void*)(Zt + srcB[i] + (kt)),       \
          (__attribute__((address_space(3))) void*)(&Bs[buf][ldsDstB[i]]), 16, 0, 0); \
  }
#define LOAD_A(kt)                                                          \
  {                                                                         \
    _Pragma("unroll")                                                       \
    for (int i = 0; i < 2; ++i) {                                           \
      ar0[i] = __builtin_nontemporal_load((const f32x4*)&A[srcAf[i] + (kt)]);        \
      ar1[i] = __builtin_nontemporal_load((const f32x4*)&A[srcAf[i] + (kt) + 4]);    \
    }                                                                       \
  }
#define WRITE_A(buf, kt, spill)                                                         \
  {                                                                                     \
    _Pragma("unroll")                                                                   \
    for (int i = 0; i < 2; ++i) {                                                       \
      unsigned u0_, u1_, u2_, u3_;                                                      \
      asm("v_cvt_pk_bf16_f32 %0, %1, %2" : "=v"(u0_) : "v"(ar0[i][0]), "v"(ar0[i][1]));\
      asm("v_cvt_pk_bf16_f32 %0, %1, %2" : "=v"(u1_) : "v"(ar0[i][2]), "v"(ar0[i][3]));\
      asm("v_cvt_pk_bf16_f32 %0, %1, %2" : "=v"(u2_) : "v"(ar1[i][0]), "v"(ar1[i][1]));\
      asm("v_cvt_pk_bf16_f32 %0, %1, %2" : "=v"(u3_) : "v"(ar1[i][2]), "v"(ar1[i][3]));\
      union { unsigned u[4]; short8v v; } pk_;                                          \
      pk_.u[0] = u0_; pk_.u[1] = u1_; pk_.u[2] = u2_; pk_.u[3] = u3_;                   \
      *(short8v*)&As[buf][dstA[i]] = pk_.v;                                             \
      if (spill) *(short8v*)&Abo[(size_t)srcAf[i] + (kt)] = pk_.v;                      \
    }                                                                                   \
  }

  f32x4 acc[2][4];
  #pragma unroll
  for (int i = 0; i < 2; ++i)
    #pragma unroll
    for (int j = 0; j < 4; ++j) acc[i][j] = (f32x4)0.f;

  // 8-wave layout: 4 rows x 2 cols of 32x64 sub-tiles
  int m0 = (wv >> 1) * 32, n0w = (wv & 1) * 64;
  int l15 = lane & 15, l4 = lane >> 4;

  int cur = 0;
  LOAD_A(k0)
  STAGE_B(0, k0)
  WRITE_A(0, k0, (cb == 0))
  __syncthreads();

  for (int it = 0; it < 64; ++it) {
    if (it + 1 < 64) {
      STAGE_B(cur ^ 1, k0 + (it + 1) * 64)
      LOAD_A(k0 + (it + 1) * 64)
    }

    #pragma unroll
    for (int kk = 0; kk < 2; ++kk) {
      int slot = kk * 4 + l4;
      short8v a[2], b[4];
      #pragma unroll
      for (int i = 0; i < 2; ++i) {
        int m = m0 + i * 16 + l15;
        a[i] = *(const short8v*)&As[cur][m * 64 + ((slot ^ (m & 7)) * 8)];
      }
      #pragma unroll
      for (int j = 0; j < 4; ++j) {
        int n = n0w + j * 16 + l15;
        b[j] = *(const short8v*)&Bs[cur][n * 64 + ((slot ^ (n & 7)) * 8)];
      }
      #pragma unroll
      for (int i = 0; i < 2; ++i)
        #pragma unroll
        for (int j = 0; j < 4; ++j)
          acc[i][j] = __builtin_amdgcn_mfma_f32_16x16x32_bf16(a[i], b[j], acc[i][j], 0, 0, 0);
    }

    if (it + 1 < 64) {
      bool sp = (cb == ((it + 1) >= 32 ? 1 : 0));
      WRITE_A(cur ^ 1, k0 + (it + 1) * 64, sp)
    }
    __syncthreads();
    cur ^= 1;
  }
#undef STAGE_B
#undef LOAD_A
#undef WRITE_A

  // C/D layout: col=lane&15, row=(lane>>4)*4+q  [m89/m91]
  int s = mat * 2 + ks;
  #pragma unroll
  for (int i = 0; i < 2; ++i) {
    #pragma unroll
    for (int j = 0; j < 4; ++j) {
      int c = n0 + n0w + j * 16 + l15;
      #pragma unroll
      for (int q = 0; q < 4; ++q) {
        int r = row0 + m0 + i * 16 + l4 * 4 + q;
        Cpart[((size_t)(s * NROW + r) << 8) + c] = acc[i][j][q];
      }
    }
  }
}

// ===========================================================================
// gemm_pair (512 threads, 8 waves, round-13 exact): stage-1 GEMMs.
// ===========================================================================
__global__ __launch_bounds__(512, 4) void gemm_pair_kernel(
    const unsigned short* __restrict__ AbF,
    const unsigned short* __restrict__ AbS,
    const unsigned short* __restrict__ ZtF,
    const unsigned short* __restrict__ ZtS,
    float* __restrict__ Cpart) {
  int d = blockIdx.x;
  int L = (d & 7) * 64 + (d >> 3);
  int mat = L & 1;
  int ks  = (L >> 1) & 1;
  int cb  = (L >> 2) & 1;
  int rb  = L >> 3;

  const unsigned short* __restrict__ Ab = mat ? AbS : AbF;
  const unsigned short* __restrict__ Zt = mat ? ZtS : ZtF;

  int t = threadIdx.x;
  int lane = t & 63, wv = t >> 6;
  int row0 = rb * 128, n0 = cb * 128, k0 = ks * 4096;

  __shared__ short As[2][128 * 64];
  __shared__ short Bs[2][128 * 64];

  int srcA[2], srcB[2], ldsDst[2];
  #pragma unroll
  for (int i = 0; i < 2; ++i) {
    int c = i * 512 + t;
    int m = c >> 3, sl = c & 7;
    int sw = ((sl ^ (m & 7)) * 8);
    srcA[i] = (row0 + m) * NROW + sw;
    srcB[i] = (n0 + m) * NROW + sw;
    ldsDst[i] = (i * 512 + wv * 64) * 8;
  }

#define STAGE_TILE(buf, kt)                                                          \
  {                                                                                  \
    _Pragma("unroll")                                                                \
    for (int i = 0; i < 2; ++i) {                                                    \
      __builtin_amdgcn_global_load_lds(                                              \
          (const __attribute__((address_space(1))) void*)(Ab + srcA[i] + (kt)),      \
          (__attribute__((address_space(3))) void*)(&As[buf][ldsDst[i]]), 16, 0, 0); \
      __builtin_amdgcn_global_load_lds(                                              \
          (const __attribute__((address_space(1))) void*)(Zt + srcB[i] + (kt)),      \
          (__attribute__((address_space(3))) void*)(&Bs[buf][ldsDst[i]]), 16, 0, 0); \
    }                                                                                \
  }

  f32x4 acc[2][4];
  #pragma unroll
  for (int i = 0; i < 2; ++i)
    #pragma unroll
    for (int j = 0; j < 4; ++j) acc[i][j] = (f32x4)0.f;

  int m0 = (wv >> 1) * 32, n0w = (wv & 1) * 64;
  int l15 = lane & 15, l4 = lane >> 4;

  int cur = 0;
  STAGE_TILE(0, k0)
  __syncthreads();

  for (int it = 0; it < 64; ++it) {
    if (it + 1 < 64) STAGE_TILE(cur ^ 1, k0 + (it + 1) * 64)

    #pragma unroll
    for (int kk = 0; kk < 2; ++kk) {
      int slot = kk * 4 + l4;
      short8v a[2], b[4];
      #pragma unroll
      for (int i = 0; i < 2; ++i) {
        int m = m0 + i * 16 + l15;
        a[i] = *(const short8v*)&As[cur][m * 64 + ((slot ^ (m & 7)) * 8)];
      }
      #pragma unroll
      for (int j = 0; j < 4; ++j) {
        int n = n0w + j * 16 + l15;
        b[j] = *(const short8v*)&Bs[cur][n * 64 + ((slot ^ (n & 7)) * 8)];
      }
      #pragma unroll
      for (int i = 0; i < 2; ++i)
        #pragma unroll
        for (int j = 0; j < 4; ++j)
          acc[i][j] = __builtin_amdgcn_mfma_f32_16x16x32_bf16(a[i], b[j], acc[i][j], 0, 0, 0);
    }
    __syncthreads();
    cur ^= 1;
  }
#undef STAGE_TILE

  int s = mat * 2 + ks;
  #pragma unroll
  for (int i = 0; i < 2; ++i) {
    #pragma unroll
    for (int j = 0; j < 4; ++j) {
      int c = n0 + n0w + j * 16 + l15;
      #pragma unroll
      for (int q = 0; q < 4; ++q) {
        int r = row0 + m0 + i * 16 + l4 * 4 + q;
        Cpart[((size_t)(s * NROW + r) << 8) + c] = acc[i][j][q];
      }
    }
  }
}

// ===========================================================================
// reduce_zmul (FUSED): stage-0 reduce -> GF0/GS0, then both stage-1 zmuls.
// ===========================================================================
__global__ __launch_bounds__(256) void reduce_zmul_kernel(
    const float* __restrict__ Cpart, const float* __restrict__ bias,
    const float* __restrict__ x, const float* __restrict__ W,
    float* __restrict__ GF0, float* __restrict__ GS0,
    unsigned short* __restrict__ ZtF, unsigned short* __restrict__ ZtS) {
  __shared__ float Ws[2500];
  __shared__ float hs[16][200];
  __shared__ float zbuf[16][256];
  int t = threadIdx.x;
  int r0 = blockIdx.x * 16;
  int w = t >> 6, j = t & 63;
  bool act = j < 50;
  int rbase = r0 + w * 4;
  for (int i = t; i < 2500; i += 256) Ws[i] = W[i];

  const float alpha[4] = {1.f, 1.f, 0.2f, 1.f};
  const float beta[4]  = {1.f, 1.f, 0.8f, 1.f};
  float gf[4][4], gs[4][4];
  if (act) {
    float bv = bias[j];
    #pragma unroll
    for (int r = 0; r < 4; ++r)
      #pragma unroll
      for (int s = 0; s < 4; ++s) {
        int c = s * 50 + j;
        size_t base = (((size_t)(rbase + r)) << 8) + c;
        float vF = Cpart[base] + Cpart[base + (size_t)NROW * 256];
        float vS = Cpart[base + (size_t)2 * NROW * 256] + Cpart[base + (size_t)3 * NROW * 256];
        gf[r][s] = fmaxf(vF + bv, 0.f);
        gs[r][s] = fmaxf(vS + bv, 0.f);
        GF0[(size_t)(rbase + r) * FEAT + c] = gf[r][s];
        GS0[(size_t)(rbase + r) * FEAT + c] = gs[r][s];
      }
    #pragma unroll
    for (int r = 0; r < 4; ++r)
      #pragma unroll
      for (int s = 0; s < 4; ++s)
        hs[w * 4 + r][s * 50 + j] =
            alpha[s] * x[(size_t)(rbase + r) * FEAT + s * 50 + j] + beta[s] * gf[r][s];
  }
  __syncthreads();
  for (int i = t; i < 16 * 256; i += 256) {
    int row = i >> 8, jj = i & 255;
    float acc = 0.f;
    if (jj < FEAT) {
      int s = jj / 50, j2 = jj % 50;
      const float* hrow = &hs[row][s * 50];
      #pragma unroll 5
      for (int k = 0; k < 50; ++k) acc += hrow[k] * Ws[k * 50 + j2];
    }
    zbuf[row][jj] = acc;
  }
  __syncthreads();
  {
    unsigned int* Ztu = (unsigned int*)ZtF;
    for (int i = t; i < 256 * 8; i += 256) {
      int j2 = i >> 3, w2 = i & 7;
      unsigned int lo = f2bf(zbuf[2 * w2][j2]);
      unsigned int hi = f2bf(zbuf[2 * w2 + 1][j2]);
      Ztu[((j2 * NROW + r0) >> 1) + w2] = lo | (hi << 16);
    }
  }
  if (act) {
    #pragma unroll
    for (int r = 0; r < 4; ++r)
      #pragma unroll
      for (int s = 0; s < 4; ++s)
        hs[w * 4 + r][s * 50 + j] =
            alpha[s] * x[(size_t)(rbase + r) * FEAT + s * 50 + j] + beta[s] * gs[r][s];
  }
  __syncthreads();
  for (int i = t; i < 16 * 256; i += 256) {
    int row = i >> 8, jj = i & 255;
    float acc = 0.f;
    if (jj < FEAT) {
      int s = jj / 50, j2 = jj % 50;
      const float* hrow = &hs[row][s * 50];
      #pragma unroll 5
      for (int k = 0; k < 50; ++k) acc += hrow[k] * Ws[k * 50 + j2];
    }
    zbuf[row][jj] = acc;
  }
  __syncthreads();
  {
    unsigned int* Ztu = (unsigned int*)ZtS;
    for (int i = t; i < 256 * 8; i += 256) {
      int j2 = i >> 3, w2 = i & 7;
      unsigned int lo = f2bf(zbuf[2 * w2][j2]);
      unsigned int hi = f2bf(zbuf[2 * w2 + 1][j2]);
      Ztu[((j2 * NROW + r0) >> 1) + w2] = lo | (hi << 16);
    }
  }
}

// ===========================================================================
// Gate helper with LDS-staged weights (round-9 verified).
// ===========================================================================
__device__ __forceinline__ void gate4(const float* __restrict__ gWi, const float* __restrict__ gbi,
                                      float* hsw, float* Wg, int t, int j, bool act,
                                      const float* h1, const float* h2, float* aout) {
  if (act) {
    #pragma unroll
    for (int r = 0; r < 4; ++r) { hsw[r * 128 + j] = h1[r]; hsw[r * 128 + 64 + j] = h2[r]; }
  }
  {
    const float4v* src = (const float4v*)gWi;
    float4v* dst = (float4v*)Wg;
    #pragma unroll
    for (int u = 0; u < 5; ++u) {
      int i = t + 256 * u;
      if (i < 1250) dst[i] = src[i];
    }
  }
  __syncthreads();
  float acc0 = 0.f, acc1 = 0.f, acc2 = 0.f, acc3 = 0.f;
  if (act) {
    float bv = gbi[j];
    acc0 = bv; acc1 = bv; acc2 = bv; acc3 = bv;
    #pragma unroll 2
    for (int k = 0; k < 50; ++k) {
      float wv = Wg[k * 50 + j];
      acc0 += hsw[0 * 128 + k] * wv;
      acc1 += hsw[1 * 128 + k] * wv;
      acc2 += hsw[2 * 128 + k] * wv;
      acc3 += hsw[3 * 128 + k] * wv;
    }
    #pragma unroll 2
    for (int k = 0; k < 50; ++k) {
      float wv = Wg[(50 + k) * 50 + j];
      acc0 += hsw[0 * 128 + 64 + k] * wv;
      acc1 += hsw[1 * 128 + 64 + k] * wv;
      acc2 += hsw[2 * 128 + 64 + k] * wv;
      acc3 += hsw[3 * 128 + 64 + k] * wv;
    }
  }
  __syncthreads();
  float accs[4] = {acc0, acc1, acc2, acc3};
  #pragma unroll
  for (int r = 0; r < 4; ++r) {
    float a = 1.f / (1.f + expf(-accs[r]));
    aout[r] = a * h1[r];
  }
}

// ===========================================================================
// reduce_chain (FUSED): stage-1 reduce + both chains + hLb pad zeroing.
// ===========================================================================
__global__ __launch_bounds__(256) void reduce_chain_kernel(
    const float* __restrict__ Cpart, const float* __restrict__ bias,
    const float* __restrict__ GF0, const float* __restrict__ GS0,
    const float* __restrict__ gW, const float* __restrict__ gb,
    unsigned short* __restrict__ hLb) {
  __shared__ float hsb[4 * 512];
  __shared__ float Wg[5000];
  int t = threadIdx.x;
  int w = t >> 6, j = t & 63;
  bool act = j < 50;
  float* hsw = &hsb[w * 512];
  int rbase = blockIdx.x * 16 + w * 4;

  float gf0[4][4], gs0[4][4], gf1[4][4], gs1[4][4];
  if (act) {
    float bv = bias[j];
    #pragma unroll
    for (int r = 0; r < 4; ++r)
      #pragma unroll
      for (int s = 0; s < 4; ++s) {
        int c = s * 50 + j;
        size_t base = (((size_t)(rbase + r)) << 8) + c;
        float vF = Cpart[base] + Cpart[base + (size_t)NROW * 256];
        float vS = Cpart[base + (size_t)2 * NROW * 256] + Cpart[base + (size_t)3 * NROW * 256];
        gf1[r][s] = fmaxf(vF + bv, 0.f);
        gs1[r][s] = fmaxf(vS + bv, 0.f);
        gf0[r][s] = GF0[(size_t)(rbase + r) * FEAT + c];
        gs0[r][s] = GS0[(size_t)(rbase + r) * FEAT + c];
      }
  }
  if (!act) {
    for (int p = j - 50; p < 48; p += 14)
      #pragma unroll
      for (int r = 0; r < 4; ++r)
        hLb[(size_t)(rbase + r) * HLK + 400 + p] = 0;
  }

  float xf2[4], xs1[4], pre[4], a[4], h1t[4], h2t[4];
  // ---- TOP chain ----
  #pragma unroll
  for (int r = 0; r < 4; ++r) xf2[r] = 0.2f * gs0[r][0] + 0.8f * gf1[r][0];
  if (act) {
    #pragma unroll
    for (int r = 0; r < 4; ++r) hLb[(size_t)(rbase + r) * HLK + 0 + j] = f2bf(xf2[r]);
  }
  #pragma unroll
  for (int r = 0; r < 4; ++r) { h1t[r] = gs0[r][0]; h2t[r] = gs0[r][1]; }
  gate4(gW + 0 * 5000, gb + 0 * 50, hsw, Wg, t, j, act, h1t, h2t, a);
  #pragma unroll
  for (int r = 0; r < 4; ++r) xs1[r] = gs0[r][1] + a[r];
  #pragma unroll
  for (int r = 0; r < 4; ++r) pre[r] = 0.2f * xs1[r] + 0.8f * gf1[r][1];
  gate4(gW + 3 * 5000, gb + 3 * 50, hsw, Wg, t, j, act, xf2, pre, a);
  #pragma unroll
  for (int r = 0; r < 4; ++r) xf2[r] = a[r] + pre[r];
  if (act) {
    #pragma unroll
    for (int r = 0; r < 4; ++r) hLb[(size_t)(rbase + r) * HLK + 100 + j] = f2bf(xf2[r]);
  }
  #pragma unroll
  for (int r = 0; r < 4; ++r) { h1t[r] = xs1[r]; h2t[r] = gs0[r][2]; }
  gate4(gW + 1 * 5000, gb + 1 * 50, hsw, Wg, t, j, act, h1t, h2t, a);
  #pragma unroll
  for (int r = 0; r < 4; ++r) xs1[r] = gs0[r][2] + a[r];
  #pragma unroll
  for (int r = 0; r < 4; ++r) pre[r] = 0.2f * xs1[r] + 0.8f * gf1[r][2];
  gate4(gW + 4 * 5000, gb + 4 * 50, hsw, Wg, t, j, act, xf2, pre, a);
  #pragma unroll
  for (int r = 0; r < 4; ++r) xf2[r] = a[r] + pre[r];
  if (act) {
    #pragma unroll
    for (int r = 0; r < 4; ++r) hLb[(size_t)(rbase + r) * HLK + 200 + j] = f2bf(xf2[r]);
  }
  #pragma unroll
  for (int r = 0; r < 4; ++r) { h1t[r] = xs1[r]; h2t[r] = gs0[r][3]; }
  gate4(gW + 2 * 5000, gb + 2 * 50, hsw, Wg, t, j, act, h1t, h2t, a);
  #pragma unroll
  for (int r = 0; r < 4; ++r) xs1[r] = gs0[r][3] + a[r];
  #pragma unroll
  for (int r = 0; r < 4; ++r) pre[r] = 0.2f * xs1[r] + 0.8f * gf1[r][3];
  gate4(gW + 5 * 5000, gb + 5 * 50, hsw, Wg, t, j, act, xf2, pre, a);
  #pragma unroll
  for (int r = 0; r < 4; ++r) xf2[r] = a[r] + pre[r];
  if (act) {
    #pragma unroll
    for (int r = 0; r < 4; ++r) hLb[(size_t)(rbase + r) * HLK + 300 + j] = f2bf(xf2[r]);
  }

  // ---- BOTTOM chain ----
  float xs2[4], xf1b[4];
  #pragma unroll
  for (int r = 0; r < 4; ++r) xs2[r] = 0.2f * gf0[r][0] + 0.8f * gs1[r][0];
  if (act) {
    #pragma unroll
    for (int r = 0; r < 4; ++r) hLb[(size_t)(rbase + r) * HLK + 50 + j] = f2bf(xs2[r]);
  }
  #pragma unroll
  for (int r = 0; r < 4; ++r) { h1t[r] = gf0[r][0]; h2t[r] = gf0[r][1]; }
  gate4(gW + 9 * 5000, gb + 9 * 50, hsw, Wg, t, j, act, h1t, h2t, a);
  #pragma unroll
  for (int r = 0; r < 4; ++r) xf1b[r] = gf0[r][1] + a[r];
  #pragma unroll
  for (int r = 0; r < 4; ++r) pre[r] = 0.2f * xf1b[r] + 0.8f * gs1[r][1];
  gate4(gW + 6 * 5000, gb + 6 * 50, hsw, Wg, t, j, act, xs2, pre, a);
  #pragma unroll
  for (int r = 0; r < 4; ++r) xs2[r] = a[r] + pre[r];
  if (act) {
    #pragma unroll
    for (int r = 0; r < 4; ++r) hLb[(size_t)(rbase + r) * HLK + 150 + j] = f2bf(xs2[r]);
  }
  #pragma unroll
  for (int r = 0; r < 4; ++r) { h1t[r] = xf1b[r]; h2t[r] = gf0[r][2]; }
  gate4(gW + 10 * 5000, gb + 10 * 50, hsw, Wg, t, j, act, h1t, h2t, a);
  #pragma unroll
  for (int r = 0; r < 4; ++r) xf1b[r] = gf0[r][2] + a[r];
  #pragma unroll
  for (int r = 0; r < 4; ++r) pre[r] = 0.2f * xf1b[r] + 0.8f * gs1[r][2];
  gate4(gW + 7 * 5000, gb + 7 * 50, hsw, Wg, t, j, act, xs2, pre, a);
  #pragma unroll
  for (int r = 0; r < 4; ++r) xs2[r] = a[r] + pre[r];
  if (act) {
    #pragma unroll
    for (int r = 0; r < 4; ++r) hLb[(size_t)(rbase + r) * HLK + 250 + j] = f2bf(xs2[r]);
  }
  #pragma unroll
  for (int r = 0; r < 4; ++r) { h1t[r] = xf1b[r]; h2t[r] = gf0[r][3]; }
  gate4(gW + 11 * 5000, gb + 11 * 50, hsw, Wg, t, j, act, h1t, h2t, a);
  #pragma unroll
  for (int r = 0; r < 4; ++r) xf1b[r] = gf0[r][3] + a[r];
  #pragma unroll
  for (int r = 0; r < 4; ++r) pre[r] = 0.2f * xf1b[r] + 0.8f * gs1[r][3];
  gate4(gW + 8 * 5000, gb + 8 * 50, hsw, Wg, t, j, act, xs2, pre, a);
  #pragma unroll
  for (int r = 0; r < 4; ++r) xs2[r] = a[r] + pre[r];
  if (act) {
    #pragma unroll
    for (int r = 0; r < 4; ++r) hLb[(size_t)(rbase + r) * HLK + 350 + j] = f2bf(xs2[r]);
  }
}

// ===========================================================================
// wconv: Wtb[n][k] = bf16(proj_W[k][n]) padded to [384][448].
// ===========================================================================
__global__ __launch_bounds__(256) void wconv_kernel(
    const float* __restrict__ pW, unsigned short* __restrict__ Wtb) {
  int i = blockIdx.x * 256 + threadIdx.x;
  if (i >= HLN * HLK) return;
  int n = i / HLK, k = i % HLK;
  float v = (n < OUTC && k < 400) ? pW[k * OUTC + n] : 0.f;
  Wtb[i] = f2bf(v);
}

// ===========================================================================
// proj_gemm: out[8192][300] = hLb[8192][448]bf16 @ Wtb^T (+pb), MFMA.
// ===========================================================================
__global__ __launch_bounds__(256, 2) void proj_gemm_kernel(
    const unsigned short* __restrict__ hLb,
    const unsigned short* __restrict__ Wtb,
    const float* __restrict__ pb, float* __restrict__ outp) {
  int d = blockIdx.x;
  int L = (d & 7) * 24 + (d >> 3);
  int rb = L / 3, cb = L % 3;

  int t = threadIdx.x;
  int lane = t & 63, wv = t >> 6;
  int row0 = rb * 128, n0 = cb * 128;

  __shared__ short As[2][128 * 64];
  __shared__ short Bs[2][128 * 64];

  int srcA[4], srcB[4], ldsDst[4];
  #pragma unroll
  for (int i = 0; i < 4; ++i) {
    int c = i * 256 + t;
    int m = c >> 3, sl = c & 7;
    int sw = ((sl ^ (m & 7)) * 8);
    srcA[i] = (row0 + m) * HLK + sw;
    srcB[i] = (n0 + m) * HLK + sw;
    ldsDst[i] = (i * 256 + wv * 64) * 8;
  }

#define STAGE_TILE(buf, kt)                                                          \
  {                                                                                  \
    _Pragma("unroll")                                                                \
    for (int i = 0; i < 4; ++i) {                                                    \
      __builtin_amdgcn_global_load_lds(                                              \
          (const __attribute__((address_space(1))) void*)(hLb + srcA[i] + (kt)),     \
          (__attribute__((address_space(3))) void*)(&As[buf][ldsDst[i]]), 16, 0, 0); \
      __builtin_amdgcn_global_load_lds(                                              \
          (const __attribute__((address_space(1))) void*)(Wtb + srcB[i] + (kt)),     \
          (__attribute__((address_space(3))) void*)(&Bs[buf][ldsDst[i]]), 16, 0, 0); \
    }                                                                                \
  }

  f32x4 acc[4][4];
  #pragma unroll
  for (int i = 0; i < 4; ++i)
    #pragma unroll
    for (int j = 0; j < 4; ++j) acc[i][j] = (f32x4)0.f;

  int m0 = (wv >> 1) * 64, n0w = (wv & 1) * 64;
  int l15 = lane & 15, l4 = lane >> 4;

  int cur = 0;
  STAGE_TILE(0, 0)
  __syncthreads();

  for (int it = 0; it < 7; ++it) {
    if (it + 1 < 7) STAGE_TILE(cur ^ 1, (it + 1) * 64)

    #pragma unroll
    for (int kk = 0; kk < 2; ++kk) {
      int slot = kk * 4 + l4;
      short8v a[4], b[4];
      #pragma unroll
      for (int i = 0; i < 4; ++i) {
        int m = m0 + i * 16 + l15;
        a[i] = *(const short8v*)&As[cur][m * 64 + ((slot ^ (m & 7)) * 8)];
        int n = n0w + i * 16 + l15;
        b[i] = *(const short8v*)&Bs[cur][n * 64 + ((slot ^ (n & 7)) * 8)];
      }
      #pragma unroll
      for (int i = 0; i < 4; ++i)
        #pragma unroll
        for (int j = 0; j < 4; ++j)
          acc[i][j] = __builtin_amdgcn_mfma_f32_16x16x32_bf16(a[i], b[j], acc[i][j], 0, 0, 0);
    }
    __syncthreads();
    cur ^= 1;
  }
#undef STAGE_TILE

  #pragma unroll
  for (int i = 0; i < 4; ++i) {
    #pragma unroll
    for (int j = 0; j < 4; ++j) {
      int c = n0 + n0w + j * 16 + l15;
      if (c < OUTC) {
        float b = pb[c];
        #pragma unroll
        for (int q = 0; q < 4; ++q) {
          int r = row0 + m0 + i * 16 + l4 * 4 + q;
          outp[(size_t)r * OUTC + c] = acc[i][j][q] + b;
        }
      }
    }
  }
}

// ===========================================================================
// f32 fallback path kernels (used only if ws too small).
// ===========================================================================
__global__ __launch_bounds__(256) void zmul_f32_kernel(
    const float* __restrict__ x, const float* __restrict__ g,
    const float* __restrict__ W,
    float a0, float a1, float a2, float a3,
    float b0, float b1, float b2, float b3,
    float* __restrict__ Zp) {
  __shared__ float Ws[2500];
  __shared__ float hs[200];
  int t = threadIdx.x;
  for (int i = t; i < 2500; i += 256) Ws[i] = W[i];
  float alpha[4] = {a0, a1, a2, a3};
  float beta[4]  = {b0, b1, b2, b3};
  int s  = (t < 200) ? (t / 50) : 0;
  int jj = (t < 200) ? (t % 50) : 0;
  int r0 = blockIdx.x * 32;
  for (int rr = 0; rr < 32; ++rr) {
    int row = r0 + rr;
    __syncthreads();
    if (t < 200) hs[t] = alpha[s] * x[row * FEAT + t] + beta[s] * g[row * FEAT + t];
    __syncthreads();
    float acc = 0.f;
    if (t < 200) {
      const float* hrow = &hs[s * 50];
      #pragma unroll 5
      for (int k = 0; k < 50; ++k) acc += hrow[k] * Ws[k * 50 + jj];
    }
    Zp[row * ZLD + t] = (t < 200) ? acc : 0.f;
  }
}

#define BM 64
#define BN 64
#define BK 32
#define ALD 68
__global__ __launch_bounds__(256) void gemm_relu_kernel(
    const float* __restrict__ A, const float* __restrict__ Zp,
    const float* __restrict__ bias, float* __restrict__ C) {
  int wg  = blockIdx.x;
  int swz = (wg & 7) * 64 + (wg >> 3);
  int rb  = swz >> 2;
  int cb  = swz & 3;
  int t   = threadIdx.x;
  int rt  = t >> 4, ct = t & 15;
  __shared__ __align__(16) float As[BK][ALD];
  __shared__ __align__(16) float Zs[BK][BN];
  float acc[4][4];
  #pragma unroll
  for (int i = 0; i < 4; ++i)
    #pragma unroll
    for (int j = 0; j < 4; ++j) acc[i][j] = 0.f;
  const int row0 = rb * BM, col0 = cb * BN;
  int ar = t >> 3;
  int ak = (t & 7) * 4;
  int zr = t >> 4;
  int zc = (t & 15) * 4;
  const float4v* A4 = (const float4v*)A;
  const float4v* Z4 = (const float4v*)Zp;
  float4v a0, a1, z0, z1;
  a0 = A4[((size_t)(row0 + ar) * NROW + 0 + ak) >> 2];
  a1 = A4[((size_t)(row0 + ar + 32) * NROW + 0 + ak) >> 2];
  z0 = Z4[((0 + zr) * ZLD + col0 + zc) >> 2];
  z1 = Z4[((0 + zr + 16) * ZLD + col0 + zc) >> 2];
  for (int kt = 0; kt < NROW; kt += BK) {
    __syncthreads();
    #pragma unroll
    for (int u = 0; u < 4; ++u) As[ak + u][ar] = a0[u];
    #pragma unroll
    for (int u = 0; u < 4; ++u) As[ak + u][ar + 32] = a1[u];
    *(float4v*)&Zs[zr][zc]      = z0;
    *(float4v*)&Zs[zr + 16][zc] = z1;
    __syncthreads();
    int kn = kt + BK;
    if (kn < NROW) {
      a0 = A4[((size_t)(row0 + ar) * NROW + kn + ak) >> 2];
      a1 = A4[((size_t)(row0 + ar + 32) * NROW + kn + ak) >> 2];
      z0 = Z4[((kn + zr) * ZLD + col0 + zc) >> 2];
      z1 = Z4[((kn + zr + 16) * ZLD + col0 + zc) >> 2];
    }
    #pragma unroll
    for (int k = 0; k < BK; ++k) {
      float4v av = *(const float4v*)&As[k][rt * 4];
      float4v zv = *(const float4v*)&Zs[k][ct * 4];
      #pragma unroll
      for (int i = 0; i < 4; ++i)
        #pragma unroll
        for (int j = 0; j < 4; ++j) acc[i][j] += av[i] * zv[j];
    }
  }
  #pragma unroll
  for (int i = 0; i < 4; ++i) {
    int grow = row0 + rt * 4 + i;
    #pragma unroll
    for (int j = 0; j < 4; ++j) {
      int gcol = col0 + ct * 4 + j;
      if (gcol < FEAT) {
        float v = acc[i][j] + bias[gcol % 50];
        C[(size_t)grow * FEAT + gcol] = fmaxf(v, 0.f);
      }
    }
  }
}

__global__ __launch_bounds__(256) void chain_top_kernel(
    const float* __restrict__ GS0, const float* __restrict__ GF1,
    const float* __restrict__ gW, const float* __restrict__ gb,
    unsigned short* __restrict__ hLb) {
  __shared__ float hsb[4 * 512];
  __shared__ float Wg[5000];
  int t = threadIdx.x;
  int w = t >> 6, j = t & 63;
  bool act = j < 50;
  float* hsw = &hsb[w * 512];
  int rbase = blockIdx.x * 16 + w * 4;
  float gs[4][4], gf[4][4];
  #pragma unroll
  for (int r = 0; r < 4; ++r)
    #pragma unroll
    for (int s = 0; s < 4; ++s) { gs[r][s] = 0.f; gf[r][s] = 0.f; }
  if (act) {
    #pragma unroll
    for (int r = 0; r < 4; ++r)
      #pragma unroll
      for (int s = 0; s < 4; ++s) {
        gs[r][s] = GS0[(size_t)(rbase + r) * FEAT + s * 50 + j];
        gf[r][s] = GF1[(size_t)(rbase + r) * FEAT + s * 50 + j];
      }
  }
  float xf2[4], xs1[4], pre[4], a[4], h1t[4], h2t[4];
  #pragma unroll
  for (int r = 0; r < 4; ++r) xf2[r] = 0.2f * gs[r][0] + 0.8f * gf[r][0];
  if (act) {
    #pragma unroll
    for (int r = 0; r < 4; ++r) hLb[(size_t)(rbase + r) * HLK + 0 + j] = f2bf(xf2[r]);
  }
  #pragma unroll
  for (int r = 0; r < 4; ++r) { h1t[r] = gs[r][0]; h2t[r] = gs[r][1]; }
  gate4(gW + 0 * 5000, gb + 0 * 50, hsw, Wg, t, j, act, h1t, h2t, a);
  #pragma unroll
  for (int r = 0; r < 4; ++r) xs1[r] = gs[r][1] + a[r];
  #pragma unroll
  for (int r = 0; r < 4; ++r) pre[r] = 0.2f * xs1[r] + 0.8f * gf[r][1];
  gate4(gW + 3 * 5000, gb + 3 * 50, hsw, Wg, t, j, act, xf2, pre, a);
  #pragma unroll
  for (int r = 0; r < 4; ++r) xf2[r] = a[r] + pre[r];
  if (act) {
    #pragma unroll
    for (int r = 0; r < 4; ++r) hLb[(size_t)(rbase + r) * HLK + 100 + j] = f2bf(xf2[r]);
  }
  #pragma unroll
  for (int r = 0; r < 4; ++r) { h1t[r] = xs1[r]; h2t[r] = gs[r][2]; }
  gate4(gW + 1 * 5000, gb + 1 * 50, hsw, Wg, t, j, act, h1t, h2t, a);
  #pragma unroll
  for (int r = 0; r < 4; ++r) xs1[r] = gs[r][2] + a[r];
  #pragma unroll
  for (int r = 0; r < 4; ++r) pre[r] = 0.2f * xs1[r] + 0.8f * gf[r][2];
  gate4(gW + 4 * 5000, gb + 4 * 50, hsw, Wg, t, j, act, xf2, pre, a);
  #pragma unroll
  for (int r = 0; r < 4; ++r) xf2[r] = a[r] + pre[r];
  if (act) {
    #pragma unroll
    for (int r = 0; r < 4; ++r) hLb[(size_t)(rbase + r) * HLK + 200 + j] = f2bf(xf2[r]);
  }
  #pragma unroll
  for (int r = 0; r < 4; ++r) { h1t[r] = xs1[r]; h2t[r] = gs[r][3]; }
  gate4(gW + 2 * 5000, gb + 2 * 50, hsw, Wg, t, j, act, h1t, h2t, a);
  #pragma unroll
  for (int r = 0; r < 4; ++r) xs1[r] = gs[r][3] + a[r];
  #pragma unroll
  for (int r = 0; r < 4; ++r) pre[r] = 0.2f * xs1[r] + 0.8f * gf[r][3];
  gate4(gW + 5 * 5000, gb + 5 * 50, hsw, Wg, t, j, act, xf2, pre, a);
  #pragma unroll
  for (int r = 0; r < 4; ++r) xf2[r] = a[r] + pre[r];
  if (act) {
    #pragma unroll
    for (int r = 0; r < 4; ++r) hLb[(size_t)(rbase + r) * HLK + 300 + j] = f2bf(xf2[r]);
  }
}

__global__ __launch_bounds__(256) void chain_bottom_kernel(
    const float* __restrict__ GF0, const float* __restrict__ GS1,
    const float* __restrict__ gW, const float* __restrict__ gb,
    unsigned short* __restrict__ hLb) {
  __shared__ float hsb[4 * 512];
  __shared__ float Wg[5000];
  int t = threadIdx.x;
  int w = t >> 6, j = t & 63;
  bool act = j < 50;
  float* hsw = &hsb[w * 512];
  int rbase = blockIdx.x * 16 + w * 4;
  float gf0[4][4], gs1[4][4];
  #pragma unroll
  for (int r = 0; r < 4; ++r)
    #pragma unroll
    for (int s = 0; s < 4; ++s) { gf0[r][s] = 0.f; gs1[r][s] = 0.f; }
  if (act) {
    #pragma unroll
    for (int r = 0; r < 4; ++r)
      #pragma unroll
      for (int s = 0; s < 4; ++s) {
        gf0[r][s] = GF0[(size_t)(rbase + r) * FEAT + s * 50 + j];
        gs1[r][s] = GS1[(size_t)(rbase + r) * FEAT + s * 50 + j];
      }
  }
  float xs2[4], xf1b[4], pre[4], a[4], h1t[4], h2t[4];
  #pragma unroll
  for (int r = 0; r < 4; ++r) xs2[r] = 0.2f * gf0[r][0] + 0.8f * gs1[r][0];
  if (act) {
    #pragma unroll
    for (int r = 0; r < 4; ++r) hLb[(size_t)(rbase + r) * HLK + 50 + j] = f2bf(xs2[r]);
  }
  #pragma unroll
  for (int r = 0; r < 4; ++r) { h1t[r] = gf0[r][0]; h2t[r] = gf0[r][1]; }
  gate4(gW + 9 * 5000, gb + 9 * 50, hsw, Wg, t, j, act, h1t, h2t, a);
  #pragma unroll
  for (int r = 0; r < 4; ++r) xf1b[r] = gf0[r][1] + a[r];
  #pragma unroll
  for (int r = 0; r < 4; ++r) pre[r] = 0.2f * xf1b[r] + 0.8f * gs1[r][1];
  gate4(gW + 6 * 5000, gb + 6 * 50, hsw, Wg, t, j, act, xs2, pre, a);
  #pragma unroll
  for (int r = 0; r < 4; ++r) xs2[r] = a[r] + pre[r];
  if (act) {
    #pragma unroll
    for (int r = 0; r < 4; ++r) hLb[(size_t)(rbase + r) * HLK + 150 + j] = f2bf(xs2[r]);
  }
  #pragma unroll
  for (int r = 0; r < 4; ++r) { h1t[r] = xf1b[r]; h2t[r] = gf0[r][2]; }
  gate4(gW + 10 * 5000, gb + 10 * 50, hsw, Wg, t, j, act, h1t, h2t, a);
  #pragma unroll
  for (int r = 0; r < 4; ++r) xf1b[r] = gf0[r][2] + a[r];
  #pragma unroll
  for (int r = 0; r < 4; ++r) pre[r] = 0.2f * xf1b[r] + 0.8f * gs1[r][2];
  gate4(gW + 7 * 5000, gb + 7 * 50, hsw, Wg, t, j, act, xs2, pre, a);
  #pragma unroll
  for (int r = 0; r < 4; ++r) xs2[r] = a[r] + pre[r];
  if (act) {
    #pragma unroll
    for (int r = 0; r < 4; ++r) hLb[(size_t)(rbase + r) * HLK + 250 + j] = f2bf(xs2[r]);
  }
  #pragma unroll
  for (int r = 0; r < 4; ++r) { h1t[r] = xf1b[r]; h2t[r] = gf0[r][3]; }
  gate4(gW + 11 * 5000, gb + 11 * 50, hsw, Wg, t, j, act, h1t, h2t, a);
  #pragma unroll
  for (int r = 0; r < 4; ++r) xf1b[r] = gf0[r][3] + a[r];
  #pragma unroll
  for (int r = 0; r < 4; ++r) pre[r] = 0.2f * xf1b[r] + 0.8f * gs1[r][3];
  gate4(gW + 8 * 5000, gb + 8 * 50, hsw, Wg, t, j, act, xs2, pre, a);
  #pragma unroll
  for (int r = 0; r < 4; ++r) xs2[r] = a[r] + pre[r];
  if (act) {
    #pragma unroll
    for (int r = 0; r < 4; ++r) hLb[(size_t)(rbase + r) * HLK + 350 + j] = f2bf(xs2[r]);
  }
}

// ===========================================================================
extern "C" void kernel_launch(void* const* d_in, const int* in_sizes, int n_in,
                              void* d_out, int out_size, void* d_ws, size_t ws_size,
                              hipStream_t stream) {
  const float* x       = (const float*)d_in[0];
  const float* A_S     = (const float*)d_in[1];
  const float* A_F     = (const float*)d_in[2];
  const float* gcn_W   = (const float*)d_in[3];
  const float* gcn_b   = (const float*)d_in[4];
  const float* gates_W = (const float*)d_in[5];
  const float* gates_b = (const float*)d_in[6];
  const float* proj_W  = (const float*)d_in[7];
  const float* proj_b  = (const float*)d_in[8];
  float* out = (float*)d_out;

  const size_t szAb    = (size_t)NROW * NROW * 2;
  const size_t szZt    = (size_t)256 * NROW * 2;
  const size_t szCpart = (size_t)4 * NROW * 256 * 4;
  const size_t szG     = (size_t)NROW * FEAT * 4;
  const size_t szHLb   = (size_t)NROW * HLK * 2;
  const size_t szWtb   = (size_t)HLN * HLK * 2;
  const size_t need = 2 * szAb + 3 * szZt + szCpart + 2 * szG + szHLb + szWtb;

  if (ws_size >= need) {
    char* w = (char*)d_ws;
    unsigned short* AbF  = (unsigned short*)w;           w += szAb;
    unsigned short* AbS  = (unsigned short*)w;           w += szAb;
    unsigned short* Zt0  = (unsigned short*)w;           w += szZt;
    unsigned short* Zt1F = (unsigned short*)w;           w += szZt;
    unsigned short* Zt1S = (unsigned short*)w;           w += szZt;
    float* Cpart = (float*)w;                            w += szCpart;
    float* GF0 = (float*)w;                              w += szG;
    float* GS0 = (float*)w;                              w += szG;
    unsigned short* hLb = (unsigned short*)w;            w += szHLb;
    unsigned short* Wtb = (unsigned short*)w;

    wconv_kernel<<<(HLN * HLK + 255) / 256, 256, 0, stream>>>(proj_W, Wtb);
    zmul_t_kernel<<<512, 256, 0, stream>>>(x, gcn_W, Zt0);

    // Stage 0: f32 A (NT stream), in-kernel cvt, balanced bf16 spill.
    gemm_cvt_spill_kernel<<<512, 512, 0, stream>>>(A_F, A_S, Zt0, Zt0, Cpart, AbF, AbS);
    reduce_zmul_kernel<<<512, 256, 0, stream>>>(Cpart, gcn_b, x, gcn_W, GF0, GS0, Zt1F, Zt1S);

    // Stage 1: bf16 A (L2/L3-hot from spill).
    gemm_pair_kernel<<<512, 512, 0, stream>>>(AbF, AbS, Zt1F, Zt1S, Cpart);
    reduce_chain_kernel<<<512, 256, 0, stream>>>(Cpart, gcn_b, GF0, GS0, gates_W, gates_b, hLb);

    proj_gemm_kernel<<<192, 256, 0, stream>>>(hLb, Wtb, proj_b, out);
  } else {
    // f32 fallback for the big GEMMs; bf16 chains + MFMA proj.
    char* w = (char*)d_ws;
    float* Z   = (float*)w;                              w += (size_t)NROW * ZLD * 4;
    float* GF0 = (float*)w;                              w += szG;
    float* GS0 = (float*)w;                              w += szG;
    float* GF1 = (float*)w;                              w += szG;
    float* GS1 = (float*)w;                              w += szG;
    unsigned short* hLb = (unsigned short*)w;            w += szHLb;
    unsigned short* Wtb = (unsigned short*)w;

    hipMemsetAsync(hLb, 0, szHLb, stream);
    wconv_kernel<<<(HLN * HLK + 255) / 256, 256, 0, stream>>>(proj_W, Wtb);

    zmul_f32_kernel<<<256, 256, 0, stream>>>(x, x, gcn_W, 1.f, 1.f, 1.f, 1.f, 0.f, 0.f, 0.f, 0.f, Z);
    gemm_relu_kernel<<<512, 256, 0, stream>>>(A_F, Z, gcn_b, GF0);
    gemm_relu_kernel<<<512, 256, 0, stream>>>(A_S, Z, gcn_b, GS0);
    zmul_f32_kernel<<<256, 256, 0, stream>>>(x, GF0, gcn_W, 1.f, 1.f, 0.2f, 1.f, 1.f, 1.f, 0.8f, 1.f, Z);
    gemm_relu_kernel<<<512, 256, 0, stream>>>(A_F, Z, gcn_b, GF1);
    zmul_f32_kernel<<<256, 256, 0, stream>>>(x, GS0, gcn_W, 1.f, 1.f, 0.2f, 1.f, 1.f, 1.f, 0.8f, 1.f, Z);
    gemm_relu_kernel<<<512, 256, 0, stream>>>(A_S, Z, gcn_b, GS1);

    chain_top_kernel<<<512, 256, 0, stream>>>(GS0, GF1, gates_W, gates_b, hLb);
    chain_bottom_kernel<<<512, 256, 0, stream>>>(GF0, GS1, gates_W, gates_b, hLb);
    proj_gemm_kernel<<<192, 256, 0, stream>>>(hLb, Wtb, proj_b, out);
  }
}

// Round 17
// 473.911 us; speedup vs baseline: 1.2760x; 1.2760x over previous
//
#include <hip/hip_runtime.h>
#include <math.h>

typedef float float4v __attribute__((ext_vector_type(4)));
typedef __attribute__((ext_vector_type(4))) float f32x4;
typedef __attribute__((ext_vector_type(8))) short short8v;
typedef __attribute__((ext_vector_type(8))) unsigned short ushort8v;

#define NROW 8192
#define FEAT 200
#define OUTC 300
#define ZLD  256
#define HLK  448
#define HLN  384

__device__ __forceinline__ unsigned short f2bf(float x) {
  unsigned u = __float_as_uint(x);
  return (unsigned short)((u + 0x7fffu + ((u >> 16) & 1u)) >> 16);  // RNE
}

// ===========================================================================
// zmul_t (stage 0): Zt0[j][row] = bf16(x @ W blockdiag).
// ===========================================================================
__global__ __launch_bounds__(256) void zmul_t_kernel(
    const float* __restrict__ x, const float* __restrict__ W,
    unsigned short* __restrict__ Zt) {
  __shared__ float Ws[2500];
  __shared__ float hs[16][200];
  __shared__ float zbuf[16][256];
  int t = threadIdx.x;
  int r0 = blockIdx.x * 16;
  for (int i = t; i < 2500; i += 256) Ws[i] = W[i];
  for (int i = t; i < 16 * FEAT; i += 256)
    hs[0][i] = x[(size_t)r0 * FEAT + i];
  __syncthreads();
  for (int i = t; i < 16 * 256; i += 256) {
    int row = i >> 8, j = i & 255;
    float acc = 0.f;
    if (j < FEAT) {
      int s = j / 50, jj = j % 50;
      const float* hrow = &hs[row][s * 50];
      #pragma unroll 5
      for (int k = 0; k < 50; ++k) acc += hrow[k] * Ws[k * 50 + jj];
    }
    zbuf[row][j] = acc;
  }
  __syncthreads();
  unsigned int* Ztu = (unsigned int*)Zt;
  for (int i = t; i < 256 * 8; i += 256) {
    int j = i >> 3, w2 = i & 7;
    unsigned int lo = f2bf(zbuf[2 * w2][j]);
    unsigned int hi = f2bf(zbuf[2 * w2 + 1][j]);
    Ztu[((j * NROW + r0) >> 1) + w2] = lo | (hi << 16);
  }
}

// ===========================================================================
// gemm_cvt_spill (round-13 best config, PLAIN f32 loads — NT reverted):
// stage-0 GEMMs, RAW F32 A. 128x128/BK=64/dbuf-64KB, 512 thr (8 waves ->
// 4 waves/SIMD at 2 blk/CU), in-kernel cvt_pk RNE, balanced spill
// (cb==0: tiles [0,32), cb==1: [32,64)).
// ===========================================================================
__global__ __launch_bounds__(512, 4) void gemm_cvt_spill_kernel(
    const float* __restrict__ AF, const float* __restrict__ AS,
    const unsigned short* __restrict__ ZtF,
    const unsigned short* __restrict__ ZtS,
    float* __restrict__ Cpart,
    unsigned short* __restrict__ AbF_o, unsigned short* __restrict__ AbS_o) {
  int d = blockIdx.x;                 // 0..511
  int L = (d & 7) * 64 + (d >> 3);    // XCD-chunked bijective
  int mat = L & 1;
  int ks  = (L >> 1) & 1;
  int cb  = (L >> 2) & 1;
  int rb  = L >> 3;                   // 0..63

  const float* __restrict__ A = mat ? AS : AF;
  const unsigned short* __restrict__ Zt = mat ? ZtS : ZtF;
  unsigned short* __restrict__ Abo = mat ? AbS_o : AbF_o;

  int t = threadIdx.x;                // 0..511
  int lane = t & 63, wv = t >> 6;     // wv 0..7
  int row0 = rb * 128, n0 = cb * 128, k0 = ks * 4096;

  __shared__ short As[2][128 * 64];
  __shared__ short Bs[2][128 * 64];

  // A reg-staging: 1024 bf16 16B chunks, 2 per thread.
  int srcAf[2], dstA[2];
  #pragma unroll
  for (int i = 0; i < 2; ++i) {
    int cc = i * 512 + t;
    int m = cc >> 3, s = cc & 7;
    srcAf[i] = (row0 + m) * NROW + s * 8;
    dstA[i] = m * 64 + ((s ^ (m & 7)) * 8);
  }
  // B staging via global_load_lds: 1024 chunks, 2 per thread.
  int srcB[2], ldsDstB[2];
  #pragma unroll
  for (int i = 0; i < 2; ++i) {
    int c = i * 512 + t;
    int m = c >> 3, sl = c & 7;
    srcB[i] = (n0 + m) * NROW + ((sl ^ (m & 7)) * 8);
    ldsDstB[i] = (i * 512 + wv * 64) * 8;
  }

  f32x4 ar0[2], ar1[2];   // 2 chunks in flight (16 VGPR)

#define STAGE_B(buf, kt)                                                              \
  {                                                                                   \
    _Pragma("unroll")                                                                 \
    for (int i = 0; i < 2; ++i)                                                       \
      __builtin_amdgcn_global_load_lds(                                               \
          (const __attribute__((address_space(1))) void*)(Zt + srcB[i] + (kt)),       \
          (__attribute__((address_space(3))) void*)(&Bs[buf][ldsDstB[i]]), 16, 0, 0); \
  }
#define LOAD_A(kt)                                         \
  {                                                        \
    _Pragma("unroll")                                      \
    for (int i = 0; i < 2; ++i) {                          \
      ar0[i] = *(const f32x4*)&A[srcAf[i] + (kt)];         \
      ar1[i] = *(const f32x4*)&A[srcAf[i] + (kt) + 4];     \
    }                                                      \
  }
#define WRITE_A(buf, kt, spill)                                                         \
  {                                                                                     \
    _Pragma("unroll")                                                                   \
    for (int i = 0; i < 2; ++i) {                                                       \
      unsigned u0_, u1_, u2_, u3_;                                                      \
      asm("v_cvt_pk_bf16_f32 %0, %1, %2" : "=v"(u0_) : "v"(ar0[i][0]), "v"(ar0[i][1]));\
      asm("v_cvt_pk_bf16_f32 %0, %1, %2" : "=v"(u1_) : "v"(ar0[i][2]), "v"(ar0[i][3]));\
      asm("v_cvt_pk_bf16_f32 %0, %1, %2" : "=v"(u2_) : "v"(ar1[i][0]), "v"(ar1[i][1]));\
      asm("v_cvt_pk_bf16_f32 %0, %1, %2" : "=v"(u3_) : "v"(ar1[i][2]), "v"(ar1[i][3]));\
      union { unsigned u[4]; short8v v; } pk_;                                          \
      pk_.u[0] = u0_; pk_.u[1] = u1_; pk_.u[2] = u2_; pk_.u[3] = u3_;                   \
      *(short8v*)&As[buf][dstA[i]] = pk_.v;                                             \
      if (spill) *(short8v*)&Abo[(size_t)srcAf[i] + (kt)] = pk_.v;                      \
    }                                                                                   \
  }

  f32x4 acc[2][4];
  #pragma unroll
  for (int i = 0; i < 2; ++i)
    #pragma unroll
    for (int j = 0; j < 4; ++j) acc[i][j] = (f32x4)0.f;

  // 8-wave layout: 4 rows x 2 cols of 32x64 sub-tiles
  int m0 = (wv >> 1) * 32, n0w = (wv & 1) * 64;
  int l15 = lane & 15, l4 = lane >> 4;

  int cur = 0;
  LOAD_A(k0)
  STAGE_B(0, k0)
  WRITE_A(0, k0, (cb == 0))
  __syncthreads();

  for (int it = 0; it < 64; ++it) {
    if (it + 1 < 64) {
      STAGE_B(cur ^ 1, k0 + (it + 1) * 64)
      LOAD_A(k0 + (it + 1) * 64)
    }

    #pragma unroll
    for (int kk = 0; kk < 2; ++kk) {
      int slot = kk * 4 + l4;
      short8v a[2], b[4];
      #pragma unroll
      for (int i = 0; i < 2; ++i) {
        int m = m0 + i * 16 + l15;
        a[i] = *(const short8v*)&As[cur][m * 64 + ((slot ^ (m & 7)) * 8)];
      }
      #pragma unroll
      for (int j = 0; j < 4; ++j) {
        int n = n0w + j * 16 + l15;
        b[j] = *(const short8v*)&Bs[cur][n * 64 + ((slot ^ (n & 7)) * 8)];
      }
      #pragma unroll
      for (int i = 0; i < 2; ++i)
        #pragma unroll
        for (int j = 0; j < 4; ++j)
          acc[i][j] = __builtin_amdgcn_mfma_f32_16x16x32_bf16(a[i], b[j], acc[i][j], 0, 0, 0);
    }

    if (it + 1 < 64) {
      bool sp = (cb == ((it + 1) >= 32 ? 1 : 0));
      WRITE_A(cur ^ 1, k0 + (it + 1) * 64, sp)
    }
    __syncthreads();
    cur ^= 1;
  }
#undef STAGE_B
#undef LOAD_A
#undef WRITE_A

  // C/D layout: col=lane&15, row=(lane>>4)*4+q  [m89/m91]
  int s = mat * 2 + ks;
  #pragma unroll
  for (int i = 0; i < 2; ++i) {
    #pragma unroll
    for (int j = 0; j < 4; ++j) {
      int c = n0 + n0w + j * 16 + l15;
      #pragma unroll
      for (int q = 0; q < 4; ++q) {
        int r = row0 + m0 + i * 16 + l4 * 4 + q;
        Cpart[((size_t)(s * NROW + r) << 8) + c] = acc[i][j][q];
      }
    }
  }
}

// ===========================================================================
// gemm_pair (512 threads, 8 waves, round-13 exact): stage-1 GEMMs.
// ===========================================================================
__global__ __launch_bounds__(512, 4) void gemm_pair_kernel(
    const unsigned short* __restrict__ AbF,
    const unsigned short* __restrict__ AbS,
    const unsigned short* __restrict__ ZtF,
    const unsigned short* __restrict__ ZtS,
    float* __restrict__ Cpart) {
  int d = blockIdx.x;
  int L = (d & 7) * 64 + (d >> 3);
  int mat = L & 1;
  int ks  = (L >> 1) & 1;
  int cb  = (L >> 2) & 1;
  int rb  = L >> 3;

  const unsigned short* __restrict__ Ab = mat ? AbS : AbF;
  const unsigned short* __restrict__ Zt = mat ? ZtS : ZtF;

  int t = threadIdx.x;
  int lane = t & 63, wv = t >> 6;
  int row0 = rb * 128, n0 = cb * 128, k0 = ks * 4096;

  __shared__ short As[2][128 * 64];
  __shared__ short Bs[2][128 * 64];

  int srcA[2], srcB[2], ldsDst[2];
  #pragma unroll
  for (int i = 0; i < 2; ++i) {
    int c = i * 512 + t;
    int m = c >> 3, sl = c & 7;
    int sw = ((sl ^ (m & 7)) * 8);
    srcA[i] = (row0 + m) * NROW + sw;
    srcB[i] = (n0 + m) * NROW + sw;
    ldsDst[i] = (i * 512 + wv * 64) * 8;
  }

#define STAGE_TILE(buf, kt)                                                          \
  {                                                                                  \
    _Pragma("unroll")                                                                \
    for (int i = 0; i < 2; ++i) {                                                    \
      __builtin_amdgcn_global_load_lds(                                              \
          (const __attribute__((address_space(1))) void*)(Ab + srcA[i] + (kt)),      \
          (__attribute__((address_space(3))) void*)(&As[buf][ldsDst[i]]), 16, 0, 0); \
      __builtin_amdgcn_global_load_lds(                                              \
          (const __attribute__((address_space(1))) void*)(Zt + srcB[i] + (kt)),      \
          (__attribute__((address_space(3))) void*)(&Bs[buf][ldsDst[i]]), 16, 0, 0); \
    }                                                                                \
  }

  f32x4 acc[2][4];
  #pragma unroll
  for (int i = 0; i < 2; ++i)
    #pragma unroll
    for (int j = 0; j < 4; ++j) acc[i][j] = (f32x4)0.f;

  int m0 = (wv >> 1) * 32, n0w = (wv & 1) * 64;
  int l15 = lane & 15, l4 = lane >> 4;

  int cur = 0;
  STAGE_TILE(0, k0)
  __syncthreads();

  for (int it = 0; it < 64; ++it) {
    if (it + 1 < 64) STAGE_TILE(cur ^ 1, k0 + (it + 1) * 64)

    #pragma unroll
    for (int kk = 0; kk < 2; ++kk) {
      int slot = kk * 4 + l4;
      short8v a[2], b[4];
      #pragma unroll
      for (int i = 0; i < 2; ++i) {
        int m = m0 + i * 16 + l15;
        a[i] = *(const short8v*)&As[cur][m * 64 + ((slot ^ (m & 7)) * 8)];
      }
      #pragma unroll
      for (int j = 0; j < 4; ++j) {
        int n = n0w + j * 16 + l15;
        b[j] = *(const short8v*)&Bs[cur][n * 64 + ((slot ^ (n & 7)) * 8)];
      }
      #pragma unroll
      for (int i = 0; i < 2; ++i)
        #pragma unroll
        for (int j = 0; j < 4; ++j)
          acc[i][j] = __builtin_amdgcn_mfma_f32_16x16x32_bf16(a[i], b[j], acc[i][j], 0, 0, 0);
    }
    __syncthreads();
    cur ^= 1;
  }
#undef STAGE_TILE

  int s = mat * 2 + ks;
  #pragma unroll
  for (int i = 0; i < 2; ++i) {
    #pragma unroll
    for (int j = 0; j < 4; ++j) {
      int c = n0 + n0w + j * 16 + l15;
      #pragma unroll
      for (int q = 0; q < 4; ++q) {
        int r = row0 + m0 + i * 16 + l4 * 4 + q;
        Cpart[((size_t)(s * NROW + r) << 8) + c] = acc[i][j][q];
      }
    }
  }
}

// ===========================================================================
// reduce_zmul (FUSED): stage-0 reduce -> GF0/GS0, then both stage-1 zmuls.
// ===========================================================================
__global__ __launch_bounds__(256) void reduce_zmul_kernel(
    const float* __restrict__ Cpart, const float* __restrict__ bias,
    const float* __restrict__ x, const float* __restrict__ W,
    float* __restrict__ GF0, float* __restrict__ GS0,
    unsigned short* __restrict__ ZtF, unsigned short* __restrict__ ZtS) {
  __shared__ float Ws[2500];
  __shared__ float hs[16][200];
  __shared__ float zbuf[16][256];
  int t = threadIdx.x;
  int r0 = blockIdx.x * 16;
  int w = t >> 6, j = t & 63;
  bool act = j < 50;
  int rbase = r0 + w * 4;
  for (int i = t; i < 2500; i += 256) Ws[i] = W[i];

  const float alpha[4] = {1.f, 1.f, 0.2f, 1.f};
  const float beta[4]  = {1.f, 1.f, 0.8f, 1.f};
  float gf[4][4], gs[4][4];
  if (act) {
    float bv = bias[j];
    #pragma unroll
    for (int r = 0; r < 4; ++r)
      #pragma unroll
      for (int s = 0; s < 4; ++s) {
        int c = s * 50 + j;
        size_t base = (((size_t)(rbase + r)) << 8) + c;
        float vF = Cpart[base] + Cpart[base + (size_t)NROW * 256];
        float vS = Cpart[base + (size_t)2 * NROW * 256] + Cpart[base + (size_t)3 * NROW * 256];
        gf[r][s] = fmaxf(vF + bv, 0.f);
        gs[r][s] = fmaxf(vS + bv, 0.f);
        GF0[(size_t)(rbase + r) * FEAT + c] = gf[r][s];
        GS0[(size_t)(rbase + r) * FEAT + c] = gs[r][s];
      }
    #pragma unroll
    for (int r = 0; r < 4; ++r)
      #pragma unroll
      for (int s = 0; s < 4; ++s)
        hs[w * 4 + r][s * 50 + j] =
            alpha[s] * x[(size_t)(rbase + r) * FEAT + s * 50 + j] + beta[s] * gf[r][s];
  }
  __syncthreads();
  for (int i = t; i < 16 * 256; i += 256) {
    int row = i >> 8, jj = i & 255;
    float acc = 0.f;
    if (jj < FEAT) {
      int s = jj / 50, j2 = jj % 50;
      const float* hrow = &hs[row][s * 50];
      #pragma unroll 5
      for (int k = 0; k < 50; ++k) acc += hrow[k] * Ws[k * 50 + j2];
    }
    zbuf[row][jj] = acc;
  }
  __syncthreads();
  {
    unsigned int* Ztu = (unsigned int*)ZtF;
    for (int i = t; i < 256 * 8; i += 256) {
      int j2 = i >> 3, w2 = i & 7;
      unsigned int lo = f2bf(zbuf[2 * w2][j2]);
      unsigned int hi = f2bf(zbuf[2 * w2 + 1][j2]);
      Ztu[((j2 * NROW + r0) >> 1) + w2] = lo | (hi << 16);
    }
  }
  if (act) {
    #pragma unroll
    for (int r = 0; r < 4; ++r)
      #pragma unroll
      for (int s = 0; s < 4; ++s)
        hs[w * 4 + r][s * 50 + j] =
            alpha[s] * x[(size_t)(rbase + r) * FEAT + s * 50 + j] + beta[s] * gs[r][s];
  }
  __syncthreads();
  for (int i = t; i < 16 * 256; i += 256) {
    int row = i >> 8, jj = i & 255;
    float acc = 0.f;
    if (jj < FEAT) {
      int s = jj / 50, j2 = jj % 50;
      const float* hrow = &hs[row][s * 50];
      #pragma unroll 5
      for (int k = 0; k < 50; ++k) acc += hrow[k] * Ws[k * 50 + j2];
    }
    zbuf[row][jj] = acc;
  }
  __syncthreads();
  {
    unsigned int* Ztu = (unsigned int*)ZtS;
    for (int i = t; i < 256 * 8; i += 256) {
      int j2 = i >> 3, w2 = i & 7;
      unsigned int lo = f2bf(zbuf[2 * w2][j2]);
      unsigned int hi = f2bf(zbuf[2 * w2 + 1][j2]);
      Ztu[((j2 * NROW + r0) >> 1) + w2] = lo | (hi << 16);
    }
  }
}

// ===========================================================================
// Gate helper with LDS-staged weights (round-9 verified).
// ===========================================================================
__device__ __forceinline__ void gate4(const float* __restrict__ gWi, const float* __restrict__ gbi,
                                      float* hsw, float* Wg, int t, int j, bool act,
                                      const float* h1, const float* h2, float* aout) {
  if (act) {
    #pragma unroll
    for (int r = 0; r < 4; ++r) { hsw[r * 128 + j] = h1[r]; hsw[r * 128 + 64 + j] = h2[r]; }
  }
  {
    const float4v* src = (const float4v*)gWi;
    float4v* dst = (float4v*)Wg;
    #pragma unroll
    for (int u = 0; u < 5; ++u) {
      int i = t + 256 * u;
      if (i < 1250) dst[i] = src[i];
    }
  }
  __syncthreads();
  float acc0 = 0.f, acc1 = 0.f, acc2 = 0.f, acc3 = 0.f;
  if (act) {
    float bv = gbi[j];
    acc0 = bv; acc1 = bv; acc2 = bv; acc3 = bv;
    #pragma unroll 2
    for (int k = 0; k < 50; ++k) {
      float wv = Wg[k * 50 + j];
      acc0 += hsw[0 * 128 + k] * wv;
      acc1 += hsw[1 * 128 + k] * wv;
      acc2 += hsw[2 * 128 + k] * wv;
      acc3 += hsw[3 * 128 + k] * wv;
    }
    #pragma unroll 2
    for (int k = 0; k < 50; ++k) {
      float wv = Wg[(50 + k) * 50 + j];
      acc0 += hsw[0 * 128 + 64 + k] * wv;
      acc1 += hsw[1 * 128 + 64 + k] * wv;
      acc2 += hsw[2 * 128 + 64 + k] * wv;
      acc3 += hsw[3 * 128 + 64 + k] * wv;
    }
  }
  __syncthreads();
  float accs[4] = {acc0, acc1, acc2, acc3};
  #pragma unroll
  for (int r = 0; r < 4; ++r) {
    float a = 1.f / (1.f + expf(-accs[r]));
    aout[r] = a * h1[r];
  }
}

// ===========================================================================
// reduce_chain (FUSED): stage-1 reduce + both chains + hLb pad zeroing.
// ===========================================================================
__global__ __launch_bounds__(256) void reduce_chain_kernel(
    const float* __restrict__ Cpart, const float* __restrict__ bias,
    const float* __restrict__ GF0, const float* __restrict__ GS0,
    const float* __restrict__ gW, const float* __restrict__ gb,
    unsigned short* __restrict__ hLb) {
  __shared__ float hsb[4 * 512];
  __shared__ float Wg[5000];
  int t = threadIdx.x;
  int w = t >> 6, j = t & 63;
  bool act = j < 50;
  float* hsw = &hsb[w * 512];
  int rbase = blockIdx.x * 16 + w * 4;

  float gf0[4][4], gs0[4][4], gf1[4][4], gs1[4][4];
  if (act) {
    float bv = bias[j];
    #pragma unroll
    for (int r = 0; r < 4; ++r)
      #pragma unroll
      for (int s = 0; s < 4; ++s) {
        int c = s * 50 + j;
        size_t base = (((size_t)(rbase + r)) << 8) + c;
        float vF = Cpart[base] + Cpart[base + (size_t)NROW * 256];
        float vS = Cpart[base + (size_t)2 * NROW * 256] + Cpart[base + (size_t)3 * NROW * 256];
        gf1[r][s] = fmaxf(vF + bv, 0.f);
        gs1[r][s] = fmaxf(vS + bv, 0.f);
        gf0[r][s] = GF0[(size_t)(rbase + r) * FEAT + c];
        gs0[r][s] = GS0[(size_t)(rbase + r) * FEAT + c];
      }
  }
  if (!act) {
    for (int p = j - 50; p < 48; p += 14)
      #pragma unroll
      for (int r = 0; r < 4; ++r)
        hLb[(size_t)(rbase + r) * HLK + 400 + p] = 0;
  }

  float xf2[4], xs1[4], pre[4], a[4], h1t[4], h2t[4];
  // ---- TOP chain ----
  #pragma unroll
  for (int r = 0; r < 4; ++r) xf2[r] = 0.2f * gs0[r][0] + 0.8f * gf1[r][0];
  if (act) {
    #pragma unroll
    for (int r = 0; r < 4; ++r) hLb[(size_t)(rbase + r) * HLK + 0 + j] = f2bf(xf2[r]);
  }
  #pragma unroll
  for (int r = 0; r < 4; ++r) { h1t[r] = gs0[r][0]; h2t[r] = gs0[r][1]; }
  gate4(gW + 0 * 5000, gb + 0 * 50, hsw, Wg, t, j, act, h1t, h2t, a);
  #pragma unroll
  for (int r = 0; r < 4; ++r) xs1[r] = gs0[r][1] + a[r];
  #pragma unroll
  for (int r = 0; r < 4; ++r) pre[r] = 0.2f * xs1[r] + 0.8f * gf1[r][1];
  gate4(gW + 3 * 5000, gb + 3 * 50, hsw, Wg, t, j, act, xf2, pre, a);
  #pragma unroll
  for (int r = 0; r < 4; ++r) xf2[r] = a[r] + pre[r];
  if (act) {
    #pragma unroll
    for (int r = 0; r < 4; ++r) hLb[(size_t)(rbase + r) * HLK + 100 + j] = f2bf(xf2[r]);
  }
  #pragma unroll
  for (int r = 0; r < 4; ++r) { h1t[r] = xs1[r]; h2t[r] = gs0[r][2]; }
  gate4(gW + 1 * 5000, gb + 1 * 50, hsw, Wg, t, j, act, h1t, h2t, a);
  #pragma unroll
  for (int r = 0; r < 4; ++r) xs1[r] = gs0[r][2] + a[r];
  #pragma unroll
  for (int r = 0; r < 4; ++r) pre[r] = 0.2f * xs1[r] + 0.8f * gf1[r][2];
  gate4(gW + 4 * 5000, gb + 4 * 50, hsw, Wg, t, j, act, xf2, pre, a);
  #pragma unroll
  for (int r = 0; r < 4; ++r) xf2[r] = a[r] + pre[r];
  if (act) {
    #pragma unroll
    for (int r = 0; r < 4; ++r) hLb[(size_t)(rbase + r) * HLK + 200 + j] = f2bf(xf2[r]);
  }
  #pragma unroll
  for (int r = 0; r < 4; ++r) { h1t[r] = xs1[r]; h2t[r] = gs0[r][3]; }
  gate4(gW + 2 * 5000, gb + 2 * 50, hsw, Wg, t, j, act, h1t, h2t, a);
  #pragma unroll
  for (int r = 0; r < 4; ++r) xs1[r] = gs0[r][3] + a[r];
  #pragma unroll
  for (int r = 0; r < 4; ++r) pre[r] = 0.2f * xs1[r] + 0.8f * gf1[r][3];
  gate4(gW + 5 * 5000, gb + 5 * 50, hsw, Wg, t, j, act, xf2, pre, a);
  #pragma unroll
  for (int r = 0; r < 4; ++r) xf2[r] = a[r] + pre[r];
  if (act) {
    #pragma unroll
    for (int r = 0; r < 4; ++r) hLb[(size_t)(rbase + r) * HLK + 300 + j] = f2bf(xf2[r]);
  }

  // ---- BOTTOM chain ----
  float xs2[4], xf1b[4];
  #pragma unroll
  for (int r = 0; r < 4; ++r) xs2[r] = 0.2f * gf0[r][0] + 0.8f * gs1[r][0];
  if (act) {
    #pragma unroll
    for (int r = 0; r < 4; ++r) hLb[(size_t)(rbase + r) * HLK + 50 + j] = f2bf(xs2[r]);
  }
  #pragma unroll
  for (int r = 0; r < 4; ++r) { h1t[r] = gf0[r][0]; h2t[r] = gf0[r][1]; }
  gate4(gW + 9 * 5000, gb + 9 * 50, hsw, Wg, t, j, act, h1t, h2t, a);
  #pragma unroll
  for (int r = 0; r < 4; ++r) xf1b[r] = gf0[r][1] + a[r];
  #pragma unroll
  for (int r = 0; r < 4; ++r) pre[r] = 0.2f * xf1b[r] + 0.8f * gs1[r][1];
  gate4(gW + 6 * 5000, gb + 6 * 50, hsw, Wg, t, j, act, xs2, pre, a);
  #pragma unroll
  for (int r = 0; r < 4; ++r) xs2[r] = a[r] + pre[r];
  if (act) {
    #pragma unroll
    for (int r = 0; r < 4; ++r) hLb[(size_t)(rbase + r) * HLK + 150 + j] = f2bf(xs2[r]);
  }
  #pragma unroll
  for (int r = 0; r < 4; ++r) { h1t[r] = xf1b[r]; h2t[r] = gf0[r][2]; }
  gate4(gW + 10 * 5000, gb + 10 * 50, hsw, Wg, t, j, act, h1t, h2t, a);
  #pragma unroll
  for (int r = 0; r < 4; ++r) xf1b[r] = gf0[r][2] + a[r];
  #pragma unroll
  for (int r = 0; r < 4; ++r) pre[r] = 0.2f * xf1b[r] + 0.8f * gs1[r][2];
  gate4(gW + 7 * 5000, gb + 7 * 50, hsw, Wg, t, j, act, xs2, pre, a);
  #pragma unroll
  for (int r = 0; r < 4; ++r) xs2[r] = a[r] + pre[r];
  if (act) {
    #pragma unroll
    for (int r = 0; r < 4; ++r) hLb[(size_t)(rbase + r) * HLK + 250 + j] = f2bf(xs2[r]);
  }
  #pragma unroll
  for (int r = 0; r < 4; ++r) { h1t[r] = xf1b[r]; h2t[r] = gf0[r][3]; }
  gate4(gW + 11 * 5000, gb + 11 * 50, hsw, Wg, t, j, act, h1t, h2t, a);
  #pragma unroll
  for (int r = 0; r < 4; ++r) xf1b[r] = gf0[r][3] + a[r];
  #pragma unroll
  for (int r = 0; r < 4; ++r) pre[r] = 0.2f * xf1b[r] + 0.8f * gs1[r][3];
  gate4(gW + 8 * 5000, gb + 8 * 50, hsw, Wg, t, j, act, xs2, pre, a);
  #pragma unroll
  for (int r = 0; r < 4; ++r) xs2[r] = a[r] + pre[r];
  if (act) {
    #pragma unroll
    for (int r = 0; r < 4; ++r) hLb[(size_t)(rbase + r) * HLK + 350 + j] = f2bf(xs2[r]);
  }
}

// ===========================================================================
// wconv: Wtb[n][k] = bf16(proj_W[k][n]) padded to [384][448].
// ===========================================================================
__global__ __launch_bounds__(256) void wconv_kernel(
    const float* __restrict__ pW, unsigned short* __restrict__ Wtb) {
  int i = blockIdx.x * 256 + threadIdx.x;
  if (i >= HLN * HLK) return;
  int n = i / HLK, k = i % HLK;
  float v = (n < OUTC && k < 400) ? pW[k * OUTC + n] : 0.f;
  Wtb[i] = f2bf(v);
}

// ===========================================================================
// proj_gemm: out[8192][300] = hLb[8192][448]bf16 @ Wtb^T (+pb), MFMA.
// ===========================================================================
__global__ __launch_bounds__(256, 2) void proj_gemm_kernel(
    const unsigned short* __restrict__ hLb,
    const unsigned short* __restrict__ Wtb,
    const float* __restrict__ pb, float* __restrict__ outp) {
  int d = blockIdx.x;
  int L = (d & 7) * 24 + (d >> 3);
  int rb = L / 3, cb = L % 3;

  int t = threadIdx.x;
  int lane = t & 63, wv = t >> 6;
  int row0 = rb * 128, n0 = cb * 128;

  __shared__ short As[2][128 * 64];
  __shared__ short Bs[2][128 * 64];

  int srcA[4], srcB[4], ldsDst[4];
  #pragma unroll
  for (int i = 0; i < 4; ++i) {
    int c = i * 256 + t;
    int m = c >> 3, sl = c & 7;
    int sw = ((sl ^ (m & 7)) * 8);
    srcA[i] = (row0 + m) * HLK + sw;
    srcB[i] = (n0 + m) * HLK + sw;
    ldsDst[i] = (i * 256 + wv * 64) * 8;
  }

#define STAGE_TILE(buf, kt)                                                          \
  {                                                                                  \
    _Pragma("unroll")                                                                \
    for (int i = 0; i < 4; ++i) {                                                    \
      __builtin_amdgcn_global_load_lds(                                              \
          (const __attribute__((address_space(1))) void*)(hLb + srcA[i] + (kt)),     \
          (__attribute__((address_space(3))) void*)(&As[buf][ldsDst[i]]), 16, 0, 0); \
      __builtin_amdgcn_global_load_lds(                                              \
          (const __attribute__((address_space(1))) void*)(Wtb + srcB[i] + (kt)),     \
          (__attribute__((address_space(3))) void*)(&Bs[buf][ldsDst[i]]), 16, 0, 0); \
    }                                                                                \
  }

  f32x4 acc[4][4];
  #pragma unroll
  for (int i = 0; i < 4; ++i)
    #pragma unroll
    for (int j = 0; j < 4; ++j) acc[i][j] = (f32x4)0.f;

  int m0 = (wv >> 1) * 64, n0w = (wv & 1) * 64;
  int l15 = lane & 15, l4 = lane >> 4;

  int cur = 0;
  STAGE_TILE(0, 0)
  __syncthreads();

  for (int it = 0; it < 7; ++it) {
    if (it + 1 < 7) STAGE_TILE(cur ^ 1, (it + 1) * 64)

    #pragma unroll
    for (int kk = 0; kk < 2; ++kk) {
      int slot = kk * 4 + l4;
      short8v a[4], b[4];
      #pragma unroll
      for (int i = 0; i < 4; ++i) {
        int m = m0 + i * 16 + l15;
        a[i] = *(const short8v*)&As[cur][m * 64 + ((slot ^ (m & 7)) * 8)];
        int n = n0w + i * 16 + l15;
        b[i] = *(const short8v*)&Bs[cur][n * 64 + ((slot ^ (n & 7)) * 8)];
      }
      #pragma unroll
      for (int i = 0; i < 4; ++i)
        #pragma unroll
        for (int j = 0; j < 4; ++j)
          acc[i][j] = __builtin_amdgcn_mfma_f32_16x16x32_bf16(a[i], b[j], acc[i][j], 0, 0, 0);
    }
    __syncthreads();
    cur ^= 1;
  }
#undef STAGE_TILE

  #pragma unroll
  for (int i = 0; i < 4; ++i) {
    #pragma unroll
    for (int j = 0; j < 4; ++j) {
      int c = n0 + n0w + j * 16 + l15;
      if (c < OUTC) {
        float b = pb[c];
        #pragma unroll
        for (int q = 0; q < 4; ++q) {
          int r = row0 + m0 + i * 16 + l4 * 4 + q;
          outp[(size_t)r * OUTC + c] = acc[i][j][q] + b;
        }
      }
    }
  }
}

// ===========================================================================
// f32 fallback path kernels (used only if ws too small).
// ===========================================================================
__global__ __launch_bounds__(256) void zmul_f32_kernel(
    const float* __restrict__ x, const float* __restrict__ g,
    const float* __restrict__ W,
    float a0, float a1, float a2, float a3,
    float b0, float b1, float b2, float b3,
    float* __restrict__ Zp) {
  __shared__ float Ws[2500];
  __shared__ float hs[200];
  int t = threadIdx.x;
  for (int i = t; i < 2500; i += 256) Ws[i] = W[i];
  float alpha[4] = {a0, a1, a2, a3};
  float beta[4]  = {b0, b1, b2, b3};
  int s  = (t < 200) ? (t / 50) : 0;
  int jj = (t < 200) ? (t % 50) : 0;
  int r0 = blockIdx.x * 32;
  for (int rr = 0; rr < 32; ++rr) {
    int row = r0 + rr;
    __syncthreads();
    if (t < 200) hs[t] = alpha[s] * x[row * FEAT + t] + beta[s] * g[row * FEAT + t];
    __syncthreads();
    float acc = 0.f;
    if (t < 200) {
      const float* hrow = &hs[s * 50];
      #pragma unroll 5
      for (int k = 0; k < 50; ++k) acc += hrow[k] * Ws[k * 50 + jj];
    }
    Zp[row * ZLD + t] = (t < 200) ? acc : 0.f;
  }
}

#define BM 64
#define BN 64
#define BK 32
#define ALD 68
__global__ __launch_bounds__(256) void gemm_relu_kernel(
    const float* __restrict__ A, const float* __restrict__ Zp,
    const float* __restrict__ bias, float* __restrict__ C) {
  int wg  = blockIdx.x;
  int swz = (wg & 7) * 64 + (wg >> 3);
  int rb  = swz >> 2;
  int cb  = swz & 3;
  int t   = threadIdx.x;
  int rt  = t >> 4, ct = t & 15;
  __shared__ __align__(16) float As[BK][ALD];
  __shared__ __align__(16) float Zs[BK][BN];
  float acc[4][4];
  #pragma unroll
  for (int i = 0; i < 4; ++i)
    #pragma unroll
    for (int j = 0; j < 4; ++j) acc[i][j] = 0.f;
  const int row0 = rb * BM, col0 = cb * BN;
  int ar = t >> 3;
  int ak = (t & 7) * 4;
  int zr = t >> 4;
  int zc = (t & 15) * 4;
  const float4v* A4 = (const float4v*)A;
  const float4v* Z4 = (const float4v*)Zp;
  float4v a0, a1, z0, z1;
  a0 = A4[((size_t)(row0 + ar) * NROW + 0 + ak) >> 2];
  a1 = A4[((size_t)(row0 + ar + 32) * NROW + 0 + ak) >> 2];
  z0 = Z4[((0 + zr) * ZLD + col0 + zc) >> 2];
  z1 = Z4[((0 + zr + 16) * ZLD + col0 + zc) >> 2];
  for (int kt = 0; kt < NROW; kt += BK) {
    __syncthreads();
    #pragma unroll
    for (int u = 0; u < 4; ++u) As[ak + u][ar] = a0[u];
    #pragma unroll
    for (int u = 0; u < 4; ++u) As[ak + u][ar + 32] = a1[u];
    *(float4v*)&Zs[zr][zc]      = z0;
    *(float4v*)&Zs[zr + 16][zc] = z1;
    __syncthreads();
    int kn = kt + BK;
    if (kn < NROW) {
      a0 = A4[((size_t)(row0 + ar) * NROW + kn + ak) >> 2];
      a1 = A4[((size_t)(row0 + ar + 32) * NROW + kn + ak) >> 2];
      z0 = Z4[((kn + zr) * ZLD + col0 + zc) >> 2];
      z1 = Z4[((kn + zr + 16) * ZLD + col0 + zc) >> 2];
    }
    #pragma unroll
    for (int k = 0; k < BK; ++k) {
      float4v av = *(const float4v*)&As[k][rt * 4];
      float4v zv = *(const float4v*)&Zs[k][ct * 4];
      #pragma unroll
      for (int i = 0; i < 4; ++i)
        #pragma unroll
        for (int j = 0; j < 4; ++j) acc[i][j] += av[i] * zv[j];
    }
  }
  #pragma unroll
  for (int i = 0; i < 4; ++i) {
    int grow = row0 + rt * 4 + i;
    #pragma unroll
    for (int j = 0; j < 4; ++j) {
      int gcol = col0 + ct * 4 + j;
      if (gcol < FEAT) {
        float v = acc[i][j] + bias[gcol % 50];
        C[(size_t)grow * FEAT + gcol] = fmaxf(v, 0.f);
      }
    }
  }
}

__global__ __launch_bounds__(256) void chain_top_kernel(
    const float* __restrict__ GS0, const float* __restrict__ GF1,
    const float* __restrict__ gW, const float* __restrict__ gb,
    unsigned short* __restrict__ hLb) {
  __shared__ float hsb[4 * 512];
  __shared__ float Wg[5000];
  int t = threadIdx.x;
  int w = t >> 6, j = t & 63;
  bool act = j < 50;
  float* hsw = &hsb[w * 512];
  int rbase = blockIdx.x * 16 + w * 4;
  float gs[4][4], gf[4][4];
  #pragma unroll
  for (int r = 0; r < 4; ++r)
    #pragma unroll
    for (int s = 0; s < 4; ++s) { gs[r][s] = 0.f; gf[r][s] = 0.f; }
  if (act) {
    #pragma unroll
    for (int r = 0; r < 4; ++r)
      #pragma unroll
      for (int s = 0; s < 4; ++s) {
        gs[r][s] = GS0[(size_t)(rbase + r) * FEAT + s * 50 + j];
        gf[r][s] = GF1[(size_t)(rbase + r) * FEAT + s * 50 + j];
      }
  }
  float xf2[4], xs1[4], pre[4], a[4], h1t[4], h2t[4];
  #pragma unroll
  for (int r = 0; r < 4; ++r) xf2[r] = 0.2f * gs[r][0] + 0.8f * gf[r][0];
  if (act) {
    #pragma unroll
    for (int r = 0; r < 4; ++r) hLb[(size_t)(rbase + r) * HLK + 0 + j] = f2bf(xf2[r]);
  }
  #pragma unroll
  for (int r = 0; r < 4; ++r) { h1t[r] = gs[r][0]; h2t[r] = gs[r][1]; }
  gate4(gW + 0 * 5000, gb + 0 * 50, hsw, Wg, t, j, act, h1t, h2t, a);
  #pragma unroll
  for (int r = 0; r < 4; ++r) xs1[r] = gs[r][1] + a[r];
  #pragma unroll
  for (int r = 0; r < 4; ++r) pre[r] = 0.2f * xs1[r] + 0.8f * gf[r][1];
  gate4(gW + 3 * 5000, gb + 3 * 50, hsw, Wg, t, j, act, xf2, pre, a);
  #pragma unroll
  for (int r = 0; r < 4; ++r) xf2[r] = a[r] + pre[r];
  if (act) {
    #pragma unroll
    for (int r = 0; r < 4; ++r) hLb[(size_t)(rbase + r) * HLK + 100 + j] = f2bf(xf2[r]);
  }
  #pragma unroll
  for (int r = 0; r < 4; ++r) { h1t[r] = xs1[r]; h2t[r] = gs[r][2]; }
  gate4(gW + 1 * 5000, gb + 1 * 50, hsw, Wg, t, j, act, h1t, h2t, a);
  #pragma unroll
  for (int r = 0; r < 4; ++r) xs1[r] = gs[r][2] + a[r];
  #pragma unroll
  for (int r = 0; r < 4; ++r) pre[r] = 0.2f * xs1[r] + 0.8f * gf[r][2];
  gate4(gW + 4 * 5000, gb + 4 * 50, hsw, Wg, t, j, act, xf2, pre, a);
  #pragma unroll
  for (int r = 0; r < 4; ++r) xf2[r] = a[r] + pre[r];
  if (act) {
    #pragma unroll
    for (int r = 0; r < 4; ++r) hLb[(size_t)(rbase + r) * HLK + 200 + j] = f2bf(xf2[r]);
  }
  #pragma unroll
  for (int r = 0; r < 4; ++r) { h1t[r] = xs1[r]; h2t[r] = gs[r][3]; }
  gate4(gW + 2 * 5000, gb + 2 * 50, hsw, Wg, t, j, act, h1t, h2t, a);
  #pragma unroll
  for (int r = 0; r < 4; ++r) xs1[r] = gs[r][3] + a[r];
  #pragma unroll
  for (int r = 0; r < 4; ++r) pre[r] = 0.2f * xs1[r] + 0.8f * gf[r][3];
  gate4(gW + 5 * 5000, gb + 5 * 50, hsw, Wg, t, j, act, xf2, pre, a);
  #pragma unroll
  for (int r = 0; r < 4; ++r) xf2[r] = a[r] + pre[r];
  if (act) {
    #pragma unroll
    for (int r = 0; r < 4; ++r) hLb[(size_t)(rbase + r) * HLK + 300 + j] = f2bf(xf2[r]);
  }
}

__global__ __launch_bounds__(256) void chain_bottom_kernel(
    const float* __restrict__ GF0, const float* __restrict__ GS1,
    const float* __restrict__ gW, const float* __restrict__ gb,
    unsigned short* __restrict__ hLb) {
  __shared__ float hsb[4 * 512];
  __shared__ float Wg[5000];
  int t = threadIdx.x;
  int w = t >> 6, j = t & 63;
  bool act = j < 50;
  float* hsw = &hsb[w * 512];
  int rbase = blockIdx.x * 16 + w * 4;
  float gf0[4][4], gs1[4][4];
  #pragma unroll
  for (int r = 0; r < 4; ++r)
    #pragma unroll
    for (int s = 0; s < 4; ++s) { gf0[r][s] = 0.f; gs1[r][s] = 0.f; }
  if (act) {
    #pragma unroll
    for (int r = 0; r < 4; ++r)
      #pragma unroll
      for (int s = 0; s < 4; ++s) {
        gf0[r][s] = GF0[(size_t)(rbase + r) * FEAT + s * 50 + j];
        gs1[r][s] = GS1[(size_t)(rbase + r) * FEAT + s * 50 + j];
      }
  }
  float xs2[4], xf1b[4], pre[4], a[4], h1t[4], h2t[4];
  #pragma unroll
  for (int r = 0; r < 4; ++r) xs2[r] = 0.2f * gf0[r][0] + 0.8f * gs1[r][0];
  if (act) {
    #pragma unroll
    for (int r = 0; r < 4; ++r) hLb[(size_t)(rbase + r) * HLK + 50 + j] = f2bf(xs2[r]);
  }
  #pragma unroll
  for (int r = 0; r < 4; ++r) { h1t[r] = gf0[r][0]; h2t[r] = gf0[r][1]; }
  gate4(gW + 9 * 5000, gb + 9 * 50, hsw, Wg, t, j, act, h1t, h2t, a);
  #pragma unroll
  for (int r = 0; r < 4; ++r) xf1b[r] = gf0[r][1] + a[r];
  #pragma unroll
  for (int r = 0; r < 4; ++r) pre[r] = 0.2f * xf1b[r] + 0.8f * gs1[r][1];
  gate4(gW + 6 * 5000, gb + 6 * 50, hsw, Wg, t, j, act, xs2, pre, a);
  #pragma unroll
  for (int r = 0; r < 4; ++r) xs2[r] = a[r] + pre[r];
  if (act) {
    #pragma unroll
    for (int r = 0; r < 4; ++r) hLb[(size_t)(rbase + r) * HLK + 150 + j] = f2bf(xs2[r]);
  }
  #pragma unroll
  for (int r = 0; r < 4; ++r) { h1t[r] = xf1b[r]; h2t[r] = gf0[r][2]; }
  gate4(gW + 10 * 5000, gb + 10 * 50, hsw, Wg, t, j, act, h1t, h2t, a);
  #pragma unroll
  for (int r = 0; r < 4; ++r) xf1b[r] = gf0[r][2] + a[r];
  #pragma unroll
  for (int r = 0; r < 4; ++r) pre[r] = 0.2f * xf1b[r] + 0.8f * gs1[r][2];
  gate4(gW + 7 * 5000, gb + 7 * 50, hsw, Wg, t, j, act, xs2, pre, a);
  #pragma unroll
  for (int r = 0; r < 4; ++r) xs2[r] = a[r] + pre[r];
  if (act) {
    #pragma unroll
    for (int r = 0; r < 4; ++r) hLb[(size_t)(rbase + r) * HLK + 250 + j] = f2bf(xs2[r]);
  }
  #pragma unroll
  for (int r = 0; r < 4; ++r) { h1t[r] = xf1b[r]; h2t[r] = gf0[r][3]; }
  gate4(gW + 11 * 5000, gb + 11 * 50, hsw, Wg, t, j, act, h1t, h2t, a);
  #pragma unroll
  for (int r = 0; r < 4; ++r) xf1b[r] = gf0[r][3] + a[r];
  #pragma unroll
  for (int r = 0; r < 4; ++r) pre[r] = 0.2f * xf1b[r] + 0.8f * gs1[r][3];
  gate4(gW + 8 * 5000, gb + 8 * 50, hsw, Wg, t, j, act, xs2, pre, a);
  #pragma unroll
  for (int r = 0; r < 4; ++r) xs2[r] = a[r] + pre[r];
  if (act) {
    #pragma unroll
    for (int r = 0; r < 4; ++r) hLb[(size_t)(rbase + r) * HLK + 350 + j] = f2bf(xs2[r]);
  }
}

// ===========================================================================
extern "C" void kernel_launch(void* const* d_in, const int* in_sizes, int n_in,
                              void* d_out, int out_size, void* d_ws, size_t ws_size,
                              hipStream_t stream) {
  const float* x       = (const float*)d_in[0];
  const float* A_S     = (const float*)d_in[1];
  const float* A_F     = (const float*)d_in[2];
  const float* gcn_W   = (const float*)d_in[3];
  const float* gcn_b   = (const float*)d_in[4];
  const float* gates_W = (const float*)d_in[5];
  const float* gates_b = (const float*)d_in[6];
  const float* proj_W  = (const float*)d_in[7];
  const float* proj_b  = (const float*)d_in[8];
  float* out = (float*)d_out;

  const size_t szAb    = (size_t)NROW * NROW * 2;
  const size_t szZt    = (size_t)256 * NROW * 2;
  const size_t szCpart = (size_t)4 * NROW * 256 * 4;
  const size_t szG     = (size_t)NROW * FEAT * 4;
  const size_t szHLb   = (size_t)NROW * HLK * 2;
  const size_t szWtb   = (size_t)HLN * HLK * 2;
  const size_t need = 2 * szAb + 3 * szZt + szCpart + 2 * szG + szHLb + szWtb;

  if (ws_size >= need) {
    char* w = (char*)d_ws;
    unsigned short* AbF  = (unsigned short*)w;           w += szAb;
    unsigned short* AbS  = (unsigned short*)w;           w += szAb;
    unsigned short* Zt0  = (unsigned short*)w;           w += szZt;
    unsigned short* Zt1F = (unsigned short*)w;           w += szZt;
    unsigned short* Zt1S = (unsigned short*)w;           w += szZt;
    float* Cpart = (float*)w;                            w += szCpart;
    float* GF0 = (float*)w;                              w += szG;
    float* GS0 = (float*)w;                              w += szG;
    unsigned short* hLb = (unsigned short*)w;            w += szHLb;
    unsigned short* Wtb = (unsigned short*)w;

    wconv_kernel<<<(HLN * HLK + 255) / 256, 256, 0, stream>>>(proj_W, Wtb);
    zmul_t_kernel<<<512, 256, 0, stream>>>(x, gcn_W, Zt0);

    // Stage 0: f32 A (plain cached loads), in-kernel cvt, balanced bf16 spill.
    gemm_cvt_spill_kernel<<<512, 512, 0, stream>>>(A_F, A_S, Zt0, Zt0, Cpart, AbF, AbS);
    reduce_zmul_kernel<<<512, 256, 0, stream>>>(Cpart, gcn_b, x, gcn_W, GF0, GS0, Zt1F, Zt1S);

    // Stage 1: bf16 A (L2/L3-hot from spill).
    gemm_pair_kernel<<<512, 512, 0, stream>>>(AbF, AbS, Zt1F, Zt1S, Cpart);
    reduce_chain_kernel<<<512, 256, 0, stream>>>(Cpart, gcn_b, GF0, GS0, gates_W, gates_b, hLb);

    proj_gemm_kernel<<<192, 256, 0, stream>>>(hLb, Wtb, proj_b, out);
  } else {
    // f32 fallback for the big GEMMs; bf16 chains + MFMA proj.
    char* w = (char*)d_ws;
    float* Z   = (float*)w;                              w += (size_t)NROW * ZLD * 4;
    float* GF0 = (float*)w;                              w += szG;
    float* GS0 = (float*)w;                              w += szG;
    float* GF1 = (float*)w;                              w += szG;
    float* GS1 = (float*)w;                              w += szG;
    unsigned short* hLb = (unsigned short*)w;            w += szHLb;
    unsigned short* Wtb = (unsigned short*)w;

    hipMemsetAsync(hLb, 0, szHLb, stream);
    wconv_kernel<<<(HLN * HLK + 255) / 256, 256, 0, stream>>>(proj_W, Wtb);

    zmul_f32_kernel<<<256, 256, 0, stream>>>(x, x, gcn_W, 1.f, 1.f, 1.f, 1.f, 0.f, 0.f, 0.f, 0.f, Z);
    gemm_relu_kernel<<<512, 256, 0, stream>>>(A_F, Z, gcn_b, GF0);
    gemm_relu_kernel<<<512, 256, 0, stream>>>(A_S, Z, gcn_b, GS0);
    zmul_f32_kernel<<<256, 256, 0, stream>>>(x, GF0, gcn_W, 1.f, 1.f, 0.2f, 1.f, 1.f, 1.f, 0.8f, 1.f, Z);
    gemm_relu_kernel<<<512, 256, 0, stream>>>(A_F, Z, gcn_b, GF1);
    zmul_f32_kernel<<<256, 256, 0, stream>>>(x, GS0, gcn_W, 1.f, 1.f, 0.2f, 1.f, 1.f, 1.f, 0.8f, 1.f, Z);
    gemm_relu_kernel<<<512, 256, 0, stream>>>(A_S, Z, gcn_b, GS1);

    chain_top_kernel<<<512, 256, 0, stream>>>(GS0, GF1, gates_W, gates_b, hLb);
    chain_bottom_kernel<<<512, 256, 0, stream>>>(GF0, GS1, gates_W, gates_b, hLb);
    proj_gemm_kernel<<<192, 256, 0, stream>>>(hLb, Wtb, proj_b, out);
  }
}